// Round 4
// baseline (270.434 us; speedup 1.0000x reference)
//
#include <hip/hip_runtime.h>
#include <math.h>

typedef unsigned short u16;
typedef unsigned int u32;

#define NCAM 6
#define NHEADS 8
#define NPOINTS 4
#define DD 256
#define HH 20
#define WW 40
#define HWSZ 800
#define LQ 4800
#define HDIM 32

typedef __attribute__((ext_vector_type(8))) short bf16x8;
typedef __attribute__((ext_vector_type(4))) float f32x4;

__device__ __forceinline__ u16 f2b(float x) {
    union { float f; u32 u; } v;
    v.f = x;
    u32 r = (v.u + 0x7FFFu + ((v.u >> 16) & 1u)) >> 16;  // RNE
    return (u16)r;
}
__device__ __forceinline__ float lo2f(u32 u) {  // low u16 as bf16 -> f32
    union { u32 u; float f; } v; v.u = u << 16; return v.f;
}
__device__ __forceinline__ float hi2f(u32 u) {  // high u16 as bf16 -> f32
    union { u32 u; float f; } v; v.u = u & 0xFFFF0000u; return v.f;
}

// ---------------------------------------------------------------------------
// pos[hw][d] fp32 + bf16 copy
__global__ __launch_bounds__(256) void pos_kernel(float* __restrict__ pos,
                                                  u16* __restrict__ posb) {
    int hw = blockIdx.x, d = threadIdx.x;
    int h = hw / WW, w = hw % WW;
    int j = (d & 127) >> 1;
    float t = powf(10000.0f, (float)j * (1.0f / 64.0f));
    float v;
    if (d < 128) v = (float)(h + 1) / (20.0f + 1e-6f) * (2.0f * (float)M_PI);
    else         v = (float)(w + 1) / (40.0f + 1e-6f) * (2.0f * (float)M_PI);
    float p = v / t;
    float r = (d & 1) ? cosf(p) : sinf(p);
    pos[hw * DD + d] = r;
    posb[hw * DD + d] = f2b(r);
}

// partial column-sums of pos over 32-row chunks: pp[25][256]
__global__ __launch_bounds__(256) void posmean(const float* __restrict__ pos,
                                               float* __restrict__ pp) {
    int i = blockIdx.x, t = threadIdx.x;
    const float* base = pos + (size_t)i * 32 * DD;
    float s = 0.f;
#pragma unroll 4
    for (int r = 0; r < 32; ++r) s += base[(size_t)r * DD + t];
    pp[i * DD + t] = s;
}

// mu_x[cam*256+c] = mean_hw x[cam][c][hw]  (row sums of original layout)
__global__ __launch_bounds__(256) void xmean(const float* __restrict__ x,
                                             float* __restrict__ mu_x) {
    int row = blockIdx.x * 4 + (threadIdx.x >> 6);  // 0..1535
    int lane = threadIdx.x & 63;
    const float* base = x + (size_t)row * HWSZ;
    float s = 0.f;
    for (int i = lane; i < HWSZ; i += 64) s += base[i];
#pragma unroll
    for (int m = 1; m <= 32; m <<= 1) s += __shfl_xor(s, m);
    if (lane == 0) mu_x[row] = s * (1.0f / (float)HWSZ);
}

// g[cam] = (mu_x[cam]@W0^T + b0 + posmean + cam_emb[cam]) @ W2^T + b2
__global__ __launch_bounds__(256) void meang2(
    const float* __restrict__ mu_x, const float* __restrict__ pp,
    const float* __restrict__ conv0_w, const float* __restrict__ conv0_b,
    const float* __restrict__ cam_emb, const float* __restrict__ conv2_w,
    const float* __restrict__ conv2_b, float* __restrict__ g) {
    int cam = blockIdx.x, t = threadIdx.x;
    __shared__ float mu[DD];
    __shared__ float smu[DD];
    float pm = 0.f;
    for (int i = 0; i < 25; ++i) pm += pp[i * DD + t];
    pm *= (1.0f / (float)HWSZ);
    mu[t] = mu_x[cam * DD + t];
    __syncthreads();
    float a = conv0_b[t] + pm + cam_emb[cam * DD + t];
    const float* wr = conv0_w + (size_t)t * DD;
    for (int k = 0; k < DD; ++k) a += mu[k] * wr[k];
    smu[t] = a;
    __syncthreads();
    float ga = conv2_b[t];
    const float* w2r = conv2_w + (size_t)t * DD;
    for (int d = 0; d < DD; ++d) ga += smu[d] * w2r[d];
    g[cam * DD + t] = ga;
}

// ---------------------------------------------------------------------------
// x [6][256][800] -> xt fp32 [4800][256] + xtb bf16
__global__ __launch_bounds__(256) void transpose_in(const float* __restrict__ x,
                                                    float* __restrict__ xt,
                                                    u16* __restrict__ xtb) {
    int cam = blockIdx.z;
    int hw0 = blockIdx.x * 32, c0 = blockIdx.y * 32;
    __shared__ float tile[32][33];
    int t = threadIdx.x;
    int lhw = t & 31, lc4 = t >> 5;
#pragma unroll
    for (int i = 0; i < 4; ++i) {
        int lc = lc4 * 4 + i;
        tile[lc][lhw] = x[((size_t)(cam * DD + c0 + lc)) * HWSZ + hw0 + lhw];
    }
    __syncthreads();
    int lc2 = t & 31, lhw4 = t >> 5;
#pragma unroll
    for (int i = 0; i < 4; ++i) {
        int lhw2 = lhw4 * 4 + i;
        float v = tile[lc2][lhw2];
        size_t idx = ((size_t)(cam * HWSZ + hw0 + lhw2)) * DD + c0 + lc2;
        xt[idx] = v;
        xtb[idx] = f2b(v);
    }
}

__global__ __launch_bounds__(256) void transpose_out(const float* __restrict__ a,
                                                     float* __restrict__ o) {
    int cam = blockIdx.z;
    int hw0 = blockIdx.x * 32, c0 = blockIdx.y * 32;
    __shared__ float tile[32][33];
    int t = threadIdx.x;
    int lc = t & 31, lhw4 = t >> 5;
#pragma unroll
    for (int i = 0; i < 4; ++i) {
        int lhw = lhw4 * 4 + i;
        tile[lhw][lc] = a[((size_t)(cam * HWSZ + hw0 + lhw)) * DD + c0 + lc];
    }
    __syncthreads();
    int lhw2 = t & 31, lc4 = t >> 5;
#pragma unroll
    for (int i = 0; i < 4; ++i) {
        int lc2 = lc4 * 4 + i;
        o[((size_t)(cam * DD + c0 + lc2)) * HWSZ + hw0 + lhw2] = tile[lhw2][lc2];
    }
}

// ---------------------------------------------------------------------------
// conversions: Wcat rows 0..255 (conv0) + offwb + lin1b + lin2b + bias_cat[0..255]
__global__ __launch_bounds__(256) void prep_weights(
    const float* __restrict__ conv0_w, const float* __restrict__ conv0_b,
    const float* __restrict__ off_w, const float* __restrict__ lin1_w,
    const float* __restrict__ lin2_w, u16* __restrict__ Wcat,
    float* __restrict__ bias_cat, u16* __restrict__ offwb,
    u16* __restrict__ lin1b, u16* __restrict__ lin2b) {
    int i = blockIdx.x * 256 + threadIdx.x;  // < 294912
    if (i < 65536) {
        Wcat[i] = f2b(conv0_w[i]);
        if (i < 256) bias_cat[i] = conv0_b[i];
    } else if (i < 163840) {
        offwb[i - 65536] = f2b(off_w[i - 65536]);
    } else if (i < 229376) {
        lin1b[i - 163840] = f2b(lin1_w[i - 163840]);
    } else {
        lin2b[i - 229376] = f2b(lin2_w[i - 229376]);
    }
}

// Wcat rows 256..1151: combined (wsrc @ W0) weights + folded biases.
// rows 256..767: kv-interleaved (head,c,kv); rows 768..1151: off rows.
__global__ __launch_bounds__(256) void wprep4(
    const float* __restrict__ conv0_w, const float* __restrict__ conv0_b,
    const float* __restrict__ key_w, const float* __restrict__ key_b,
    const float* __restrict__ val_w, const float* __restrict__ val_b,
    const float* __restrict__ off_w, const float* __restrict__ off_b,
    u16* __restrict__ Wcat, float* __restrict__ bias_cat) {
    int rbase = 256 + blockIdx.x * 4;  // 256..1148
    int t = threadIdx.x;
    __shared__ float rowv[4][DD];
    __shared__ float cb[DD];
    cb[t] = conv0_b[t];
#pragma unroll
    for (int j = 0; j < 4; ++j) {
        int row = rbase + j;
        const float* srcp;
        if (row < 768) {
            int rj = row - 256;
            int head = rj >> 6, cpair = (rj >> 1) & 31, kv = rj & 1;
            srcp = (kv ? val_w : key_w) + (size_t)(head * 32 + cpair) * DD;
        } else {
            srcp = off_w + (size_t)(row - 768) * DD;
        }
        rowv[j][t] = srcp[t];
    }
    __syncthreads();
    float acc[4] = {0.f, 0.f, 0.f, 0.f};
    for (int c = 0; c < DD; ++c) {
        float w0 = conv0_w[(size_t)c * DD + t];
#pragma unroll
        for (int j = 0; j < 4; ++j) acc[j] += rowv[j][c] * w0;
    }
#pragma unroll
    for (int j = 0; j < 4; ++j) Wcat[(size_t)(rbase + j) * DD + t] = f2b(acc[j]);
    if (t < 4) {
        int row = rbase + t;
        float b;
        if (row < 768) {
            int rj = row - 256;
            int head = rj >> 6, cpair = (rj >> 1) & 31, kv = rj & 1;
            b = (kv ? val_b : key_b)[head * 32 + cpair];
        } else {
            b = off_b[row - 768];
        }
        for (int c = 0; c < DD; ++c) b += rowv[t][c] * cb[c];
        bias_cat[row] = b;
    }
}

// W_comb = conv1_w @ out_w (bf16) ; b_comb = conv1_w @ out_b + conv1_b
__global__ __launch_bounds__(256) void wcomb_kernel(const float* __restrict__ conv1_w,
                                                    const float* __restrict__ out_w,
                                                    const float* __restrict__ out_b,
                                                    const float* __restrict__ conv1_b,
                                                    u16* __restrict__ Wc,
                                                    float* __restrict__ bc) {
    int n = blockIdx.x, t = threadIdx.x;
    __shared__ float rowv[DD];
    rowv[t] = conv1_w[(size_t)n * DD + t];
    __syncthreads();
    float acc = 0.f;
    for (int m = 0; m < DD; ++m) acc += rowv[m] * out_w[(size_t)m * DD + t];
    Wc[(size_t)n * DD + t] = f2b(acc);
    if (t == 0) {
        float b = conv1_b[n];
        for (int m = 0; m < DD; ++m) b += rowv[m] * out_b[m];
        bc[n] = b;
    }
}

// camoff[cam][n] = cam_emb[cam] @ off_w^T   (6 blocks x 384 threads)
__global__ __launch_bounds__(384) void camoff_kernel(const float* __restrict__ cam_emb,
                                                     const float* __restrict__ off_w,
                                                     float* __restrict__ camoff) {
    int cam = blockIdx.x, t = threadIdx.x;  // t < 384
    __shared__ float ce[DD];
    if (t < DD) ce[t] = cam_emb[cam * DD + t];
    __syncthreads();
    float a = 0.f;
    const float* wr = off_w + (size_t)t * DD;
    for (int c = 0; c < DD; ++c) a += ce[c] * wr[c];
    camoff[cam * 384 + t] = a;
}

// ---------------------------------------------------------------------------
// bf16 MFMA GEMM (BM=32, BN=128): C = A@W^T (+bias). mode 0: fp32 out, 1: relu bf16
__global__ __launch_bounds__(256) void gemm_bf16(
    const u16* __restrict__ Ab, const u16* __restrict__ Wb,
    const float* __restrict__ bias, float* __restrict__ C,
    u16* __restrict__ Cb, int N, int mode) {
    __shared__ __align__(16) u16 As[1056];
    __shared__ __align__(16) u16 Bs[4120];
    int t = threadIdx.x;
    int col0 = blockIdx.x * 128, row0 = blockIdx.y * 32;
    int wv = t >> 6, lane = t & 63;
    int quad = lane >> 4, l = lane & 15;
    f32x4 acc[2][2] = {};
    for (int k0 = 0; k0 < 256; k0 += 32) {
        __syncthreads();
        if (t < 128) {
            int m = t >> 2, j = t & 3;
            *(uint4*)&As[(j * 33 + m) * 8] =
                *(const uint4*)&Ab[(size_t)(row0 + m) * 256 + k0 + j * 8];
        }
        {
            int n = t >> 1, jp = (t & 1) * 2;
            const u16* gsrc = &Wb[(size_t)(col0 + n) * 256 + k0 + jp * 8];
            *(uint4*)&Bs[(jp * 129 + n) * 8]       = *(const uint4*)gsrc;
            *(uint4*)&Bs[((jp + 1) * 129 + n) * 8] = *(const uint4*)(gsrc + 8);
        }
        __syncthreads();
        bf16x8 a0 = *(const bf16x8*)&As[(quad * 33 + l) * 8];
        bf16x8 a1 = *(const bf16x8*)&As[(quad * 33 + 16 + l) * 8];
        bf16x8 b0 = *(const bf16x8*)&Bs[(quad * 129 + wv * 32 + l) * 8];
        bf16x8 b1 = *(const bf16x8*)&Bs[(quad * 129 + wv * 32 + 16 + l) * 8];
        acc[0][0] = __builtin_amdgcn_mfma_f32_16x16x32_bf16(a0, b0, acc[0][0], 0, 0, 0);
        acc[0][1] = __builtin_amdgcn_mfma_f32_16x16x32_bf16(a0, b1, acc[0][1], 0, 0, 0);
        acc[1][0] = __builtin_amdgcn_mfma_f32_16x16x32_bf16(a1, b0, acc[1][0], 0, 0, 0);
        acc[1][1] = __builtin_amdgcn_mfma_f32_16x16x32_bf16(a1, b1, acc[1][1], 0, 0, 0);
    }
#pragma unroll
    for (int mt = 0; mt < 2; ++mt) {
#pragma unroll
        for (int nt = 0; nt < 2; ++nt) {
            int col = col0 + wv * 32 + nt * 16 + l;
            float bb = bias ? bias[col] : 0.f;
#pragma unroll
            for (int r = 0; r < 4; ++r) {
                int row = row0 + mt * 16 + quad * 4 + r;
                float v = acc[mt][nt][r] + bb;
                size_t oi = (size_t)row * N + col;
                if (mode == 0) C[oi] = v;
                else           Cb[oi] = f2b(fmaxf(v, 0.f));
            }
        }
    }
}

// ---------------------------------------------------------------------------
// Fused N=1152 GEMM on xtb: cols 0..255 conv0->spcb(+pos+cam), 256..767 kv->bf16,
// 768..1151 offsets->fp32
__global__ __launch_bounds__(256) void gemm_fused(
    const u16* __restrict__ Ab, const u16* __restrict__ Wcat,
    const float* __restrict__ bias_cat, const float* __restrict__ pos,
    const float* __restrict__ cam_emb, u16* __restrict__ spcb,
    u16* __restrict__ kvcat16, float* __restrict__ offs) {
    __shared__ __align__(16) u16 As[1056];
    __shared__ __align__(16) u16 Bs[4120];
    int t = threadIdx.x;
    int col0 = blockIdx.x * 128, row0 = blockIdx.y * 32;
    int wv = t >> 6, lane = t & 63;
    int quad = lane >> 4, l = lane & 15;
    f32x4 acc[2][2] = {};
    for (int k0 = 0; k0 < 256; k0 += 32) {
        __syncthreads();
        if (t < 128) {
            int m = t >> 2, j = t & 3;
            *(uint4*)&As[(j * 33 + m) * 8] =
                *(const uint4*)&Ab[(size_t)(row0 + m) * 256 + k0 + j * 8];
        }
        {
            int n = t >> 1, jp = (t & 1) * 2;
            const u16* gsrc = &Wcat[(size_t)(col0 + n) * 256 + k0 + jp * 8];
            *(uint4*)&Bs[(jp * 129 + n) * 8]       = *(const uint4*)gsrc;
            *(uint4*)&Bs[((jp + 1) * 129 + n) * 8] = *(const uint4*)(gsrc + 8);
        }
        __syncthreads();
        bf16x8 a0 = *(const bf16x8*)&As[(quad * 33 + l) * 8];
        bf16x8 a1 = *(const bf16x8*)&As[(quad * 33 + 16 + l) * 8];
        bf16x8 b0 = *(const bf16x8*)&Bs[(quad * 129 + wv * 32 + l) * 8];
        bf16x8 b1 = *(const bf16x8*)&Bs[(quad * 129 + wv * 32 + 16 + l) * 8];
        acc[0][0] = __builtin_amdgcn_mfma_f32_16x16x32_bf16(a0, b0, acc[0][0], 0, 0, 0);
        acc[0][1] = __builtin_amdgcn_mfma_f32_16x16x32_bf16(a0, b1, acc[0][1], 0, 0, 0);
        acc[1][0] = __builtin_amdgcn_mfma_f32_16x16x32_bf16(a1, b0, acc[1][0], 0, 0, 0);
        acc[1][1] = __builtin_amdgcn_mfma_f32_16x16x32_bf16(a1, b1, acc[1][1], 0, 0, 0);
    }
#pragma unroll
    for (int mt = 0; mt < 2; ++mt) {
#pragma unroll
        for (int nt = 0; nt < 2; ++nt) {
            int col = col0 + wv * 32 + nt * 16 + l;
            float bb = bias_cat[col];
#pragma unroll
            for (int r = 0; r < 4; ++r) {
                int row = row0 + mt * 16 + quad * 4 + r;
                float v = acc[mt][nt][r] + bb;
                if (col0 < 256) {
                    int cam = row / HWSZ, hw = row % HWSZ;
                    spcb[(size_t)row * 256 + col] =
                        f2b(v + pos[(size_t)hw * 256 + col] + cam_emb[cam * 256 + col]);
                } else if (col0 < 768) {
                    kvcat16[(size_t)row * 512 + (col - 256)] = f2b(v);
                } else {
                    offs[(size_t)row * 384 + (col - 768)] = v;
                }
            }
        }
    }
}

// ---------------------------------------------------------------------------
// Deformable attention v3: 2 queries/block, 16 lanes/head (2 channels/lane),
// staged bilinear addresses/weights, bf16 kv gathers, batched online softmax.
__global__ __launch_bounds__(256, 6) void attn_kernel(
    const u16* __restrict__ spcb, const u16* __restrict__ kvcat16,
    const float* __restrict__ offs, const float* __restrict__ posoff,
    const float* __restrict__ camoff, const float* __restrict__ g,
    u16* __restrict__ attn_out) {
    int qq = blockIdx.x;
    int q0 = qq * 2;
    int tid = threadIdx.x;
    int cam = q0 / HWSZ;   // same cam for q0, q0+1 (HWSZ even)
    int hw0 = q0 % HWSZ;
    __shared__ float soff[2][384];
    __shared__ float wgt[2][192][4];
    __shared__ int   idxp[2][192][4];
    for (int i = tid; i < 768; i += 256) {
        int qi = i / 384, n = i - qi * 384;
        soff[qi][n] = offs[(size_t)(q0 + qi) * 384 + n] +
                      posoff[(size_t)(hw0 + qi) * 384 + n] + camoff[cam * 384 + n];
    }
    __syncthreads();
    for (int e2 = tid; e2 < 384; e2 += 256) {
        int qi = e2 / 192, e = e2 - qi * 192;
        int head = e / 24, r = e - head * 24;
        int scam = r >> 2;
        int hw = hw0 + qi;
        int h = hw / WW, w = hw - h * WW;
        float X = (float)w + soff[qi][e * 2];
        float Y = (float)h + soff[qi][e * 2 + 1];
        float x0f = floorf(X), y0f = floorf(Y);
        float fx = X - x0f, fy = Y - y0f;
        int x0 = (int)x0f, y0 = (int)y0f, x1 = x0 + 1, y1 = y0 + 1;
        float vx0 = (x0 >= 0 && x0 < WW) ? 1.f : 0.f;
        float vx1 = (x1 >= 0 && x1 < WW) ? 1.f : 0.f;
        float vy0 = (y0 >= 0 && y0 < HH) ? 1.f : 0.f;
        float vy1 = (y1 >= 0 && y1 < HH) ? 1.f : 0.f;
        int cx0 = min(max(x0, 0), WW - 1), cx1 = min(max(x1, 0), WW - 1);
        int cy0 = min(max(y0, 0), HH - 1), cy1 = min(max(y1, 0), HH - 1);
        wgt[qi][e][0] = (1.f - fx) * (1.f - fy) * vx0 * vy0;
        wgt[qi][e][1] = fx * (1.f - fy) * vx1 * vy0;
        wgt[qi][e][2] = (1.f - fx) * fy * vx0 * vy1;
        wgt[qi][e][3] = fx * fy * vx1 * vy1;
        int pb = scam * HWSZ;
        int hb = head * 64;
        idxp[qi][e][0] = ((pb + cy0 * WW + cx0) << 9) + hb;
        idxp[qi][e][1] = ((pb + cy0 * WW + cx1) << 9) + hb;
        idxp[qi][e][2] = ((pb + cy1 * WW + cx0) << 9) + hb;
        idxp[qi][e][3] = ((pb + cy1 * WW + cx1) << 9) + hb;
    }
    __syncthreads();
    int qi = tid >> 7, head = (tid >> 4) & 7, l = tid & 15;
    int q = q0 + qi;
    int c0 = l * 2;
    u32 qu = *(const u32*)&spcb[(size_t)q * 256 + head * 32 + c0];
    const float scale = 0.17677669529663687f;  // 1/sqrt(32)
    float q0s = lo2f(qu) * scale, q1s = hi2f(qu) * scale;
    float m = -1e30f, den = 0.f, o0 = 0.f, o1 = 0.f;
    for (int sc = 0; sc < NCAM; ++sc) {
        float av0[4], av1[4], lg[4];
#pragma unroll
        for (int p = 0; p < 4; ++p) {
            int e = head * 24 + sc * 4 + p;
            float ak0 = 0.f, ak1 = 0.f, a0 = 0.f, a1 = 0.f;
#pragma unroll
            for (int j = 0; j < 4; ++j) {
                int idx = idxp[qi][e][j] + 4 * l;
                float wj = wgt[qi][e][j];
                uint2 d = *(const uint2*)&kvcat16[idx];  // k0,v0,k1,v1
                ak0 += wj * lo2f(d.x);
                a0  += wj * hi2f(d.x);
                ak1 += wj * lo2f(d.y);
                a1  += wj * hi2f(d.y);
            }
            av0[p] = a0; av1[p] = a1;
            float pl = q0s * ak0 + q1s * ak1;
            pl += __shfl_xor(pl, 1);
            pl += __shfl_xor(pl, 2);
            pl += __shfl_xor(pl, 4);
            pl += __shfl_xor(pl, 8);
            lg[p] = pl;
        }
        float2 gv = *(const float2*)&g[sc * 256 + head * 32 + c0];
        float pg = q0s * gv.x + q1s * gv.y;
        pg += __shfl_xor(pg, 1);
        pg += __shfl_xor(pg, 2);
        pg += __shfl_xor(pg, 4);
        pg += __shfl_xor(pg, 8);
        // batched online-softmax update (5 logits)
        float mc = fmaxf(fmaxf(fmaxf(lg[0], lg[1]), fmaxf(lg[2], lg[3])), pg);
        float mn = fmaxf(m, mc);
        float aa = __expf(m - mn);
        float e0p = __expf(lg[0] - mn), e1p = __expf(lg[1] - mn);
        float e2p = __expf(lg[2] - mn), e3p = __expf(lg[3] - mn);
        float e4p = __expf(pg - mn);
        den = den * aa + (e0p + e1p + e2p + e3p + e4p);
        o0 = o0 * aa + e0p * av0[0] + e1p * av0[1] + e2p * av0[2] + e3p * av0[3] + e4p * gv.x;
        o1 = o1 * aa + e0p * av1[0] + e1p * av1[1] + e2p * av1[2] + e3p * av1[3] + e4p * gv.y;
        m = mn;
    }
    float inv = 1.f / den;
    u32 pack = (u32)f2b(o0 * inv) | ((u32)f2b(o1 * inv) << 16);
    *(u32*)&attn_out[(size_t)q * 256 + head * 32 + c0] = pack;
}

// ---------------------------------------------------------------------------
// Fused GEMM (N=256) + residual + LayerNorm. BM=16, grid 300.
// C = LN(A@W^T + bias + e0) * gamma + beta ; optional bf16 copy Cb.
__global__ __launch_bounds__(256) void gemm_ln(
    const u16* __restrict__ Ab, const u16* __restrict__ Wb,
    const float* __restrict__ bias, const float* __restrict__ e0,
    const float* __restrict__ gamma, const float* __restrict__ beta,
    float* __restrict__ C, u16* __restrict__ Cb) {
    __shared__ __align__(16) u16 As[552];    // 4*17*8 + pad
    __shared__ __align__(16) u16 Bs[8232];   // 4*257*8 + pad
    __shared__ float red[4][4][4][2];        // [wv][quad][r][{sum,sumsq}]
    int t = threadIdx.x;
    int row0 = blockIdx.x * 16;
    int wv = t >> 6, lane = t & 63, quad = lane >> 4, l = lane & 15;
    f32x4 acc[4] = {};
    for (int k0 = 0; k0 < 256; k0 += 32) {
        __syncthreads();
        if (t < 64) {
            int mm = t >> 2, j = t & 3;
            *(uint4*)&As[(j * 17 + mm) * 8] =
                *(const uint4*)&Ab[(size_t)(row0 + mm) * 256 + k0 + j * 8];
        }
#pragma unroll
        for (int j = 0; j < 4; ++j)
            *(uint4*)&Bs[(j * 257 + t) * 8] =
                *(const uint4*)&Wb[(size_t)t * 256 + k0 + j * 8];
        __syncthreads();
        bf16x8 a = *(const bf16x8*)&As[(quad * 17 + l) * 8];
#pragma unroll
        for (int nt = 0; nt < 4; ++nt) {
            bf16x8 b = *(const bf16x8*)&Bs[(quad * 257 + wv * 64 + nt * 16 + l) * 8];
            acc[nt] = __builtin_amdgcn_mfma_f32_16x16x32_bf16(a, b, acc[nt], 0, 0, 0);
        }
    }
    float v[4][4];
    float g4[4], b4[4];
#pragma unroll
    for (int nt = 0; nt < 4; ++nt) {
        int col = wv * 64 + nt * 16 + l;
        float bb = bias[col];
        g4[nt] = gamma[col];
        b4[nt] = beta[col];
#pragma unroll
        for (int r = 0; r < 4; ++r) {
            int row = row0 + quad * 4 + r;
            v[nt][r] = acc[nt][r] + bb + e0[(size_t)row * 256 + col];
        }
    }
#pragma unroll
    for (int r = 0; r < 4; ++r) {
        float s = v[0][r] + v[1][r] + v[2][r] + v[3][r];
        float sq = v[0][r] * v[0][r] + v[1][r] * v[1][r] +
                   v[2][r] * v[2][r] + v[3][r] * v[3][r];
#pragma unroll
        for (int msk = 1; msk <= 8; msk <<= 1) {
            s += __shfl_xor(s, msk);
            sq += __shfl_xor(sq, msk);
        }
        if (l == 0) { red[wv][quad][r][0] = s; red[wv][quad][r][1] = sq; }
    }
    __syncthreads();
#pragma unroll
    for (int r = 0; r < 4; ++r) {
        float S = red[0][quad][r][0] + red[1][quad][r][0] +
                  red[2][quad][r][0] + red[3][quad][r][0];
        float Q = red[0][quad][r][1] + red[1][quad][r][1] +
                  red[2][quad][r][1] + red[3][quad][r][1];
        float mean = S * (1.0f / 256.0f);
        float var = Q * (1.0f / 256.0f) - mean * mean;
        float rstd = rsqrtf(var + 1e-5f);
        int row = row0 + quad * 4 + r;
#pragma unroll
        for (int nt = 0; nt < 4; ++nt) {
            int col = wv * 64 + nt * 16 + l;
            float ov = (v[nt][r] - mean) * rstd * g4[nt] + b4[nt];
            C[(size_t)row * 256 + col] = ov;
            if (Cb) Cb[(size_t)row * 256 + col] = f2b(ov);
        }
    }
}

// ---------------------------------------------------------------------------
extern "C" void kernel_launch(void* const* d_in, const int* in_sizes, int n_in,
                              void* d_out, int out_size, void* d_ws, size_t ws_size,
                              hipStream_t stream) {
    const float* x       = (const float*)d_in[0];
    const float* conv0_w = (const float*)d_in[1];
    const float* conv0_b = (const float*)d_in[2];
    const float* conv2_w = (const float*)d_in[3];
    const float* conv2_b = (const float*)d_in[4];
    const float* cam_emb = (const float*)d_in[5];
    const float* off_w   = (const float*)d_in[6];
    const float* off_b   = (const float*)d_in[7];
    const float* val_w   = (const float*)d_in[8];
    const float* val_b   = (const float*)d_in[9];
    const float* key_w   = (const float*)d_in[10];
    const float* key_b   = (const float*)d_in[11];
    const float* out_w   = (const float*)d_in[12];
    const float* out_b   = (const float*)d_in[13];
    const float* conv1_w = (const float*)d_in[14];
    const float* conv1_b = (const float*)d_in[15];
    const float* norm0_g = (const float*)d_in[16];
    const float* norm0_b = (const float*)d_in[17];
    const float* lin1_w  = (const float*)d_in[18];
    const float* lin1_b  = (const float*)d_in[19];
    const float* lin2_w  = (const float*)d_in[20];
    const float* lin2_b  = (const float*)d_in[21];
    const float* norm2_g = (const float*)d_in[22];
    const float* norm2_b = (const float*)d_in[23];

    float* ws = (float*)d_ws;
    const size_t SZ = (size_t)LQ * DD;  // 1,228,800
    float* pos      = ws;                       // 204800
    float* pp       = pos + 204800;             // 6400
    float* mu_x     = pp + 6400;                // 1536
    float* g        = mu_x + 1536;              // 1536
    float* camoff   = g + 1536;                 // 2304
    float* posoff   = camoff + 2304;            // 307200
    float* bias_cat = posoff + 307200;          // 1152
    float* bcomb    = bias_cat + 1152;          // 256
    float* xt       = bcomb + 256;              // SZ   (aliased later: out_ln)
    float* offs     = xt + SZ;                  // 1843200 (alias: out0 + out0b)
    float* f_posb   = offs + 1843200;           // 102400
    float* f_xtb    = f_posb + 102400;          // 614400 (alias: attn_ob)
    float* f_spcb   = f_xtb + 614400;           // 614400
    float* f_kvcat  = f_spcb + 614400;          // 1228800 (alias: hidden)
    float* f_Wcat   = f_kvcat + 1228800;        // 147456
    float* f_offwb  = f_Wcat + 147456;          // 49152
    float* f_lin1b  = f_offwb + 49152;          // 32768
    float* f_lin2b  = f_lin1b + 32768;          // 32768
    float* f_wcombb = f_lin2b + 32768;          // 32768

    u16* posb    = (u16*)f_posb;
    u16* xtb     = (u16*)f_xtb;
    u16* spcb    = (u16*)f_spcb;
    u16* kvcat16 = (u16*)f_kvcat;
    u16* Wcat    = (u16*)f_Wcat;
    u16* offwb   = (u16*)f_offwb;
    u16* lin1b   = (u16*)f_lin1b;
    u16* lin2b   = (u16*)f_lin2b;
    u16* wcombb  = (u16*)f_wcombb;
    // aliases (disjoint lifetimes)
    u16*   attn_ob = xtb;                 // xtb dead after gemm_fused
    float* out0    = offs;                // offs dead after attn
    u16*   out0b   = (u16*)(offs + SZ);   // fits: SZ + SZ/2 = 1843200
    u16*   hidden  = kvcat16;             // kvcat dead after attn
    float* out_ln  = xt;                  // xt dead after gemm_ln(comb)

    dim3 tgrid(25, 8, NCAM);

    pos_kernel<<<HWSZ, 256, 0, stream>>>(pos, posb);
    transpose_in<<<tgrid, 256, 0, stream>>>(x, xt, xtb);
    xmean<<<384, 256, 0, stream>>>(x, mu_x);
    posmean<<<25, 256, 0, stream>>>(pos, pp);
    prep_weights<<<1152, 256, 0, stream>>>(conv0_w, conv0_b, off_w, lin1_w, lin2_w,
                                           Wcat, bias_cat, offwb, lin1b, lin2b);
    wprep4<<<224, 256, 0, stream>>>(conv0_w, conv0_b, key_w, key_b, val_w, val_b,
                                    off_w, off_b, Wcat, bias_cat);
    wcomb_kernel<<<DD, 256, 0, stream>>>(conv1_w, out_w, out_b, conv1_b, wcombb, bcomb);
    camoff_kernel<<<NCAM, 384, 0, stream>>>(cam_emb, off_w, camoff);
    meang2<<<NCAM, 256, 0, stream>>>(mu_x, pp, conv0_w, conv0_b, cam_emb,
                                     conv2_w, conv2_b, g);
    // posoff = pos @ off_w^T  (bf16 MFMA, no bias)
    gemm_bf16<<<dim3(3, 25), 256, 0, stream>>>(posb, offwb, nullptr, posoff,
                                               nullptr, 384, 0);
    // fused conv0 + kv + off GEMM on xtb
    gemm_fused<<<dim3(9, 150), 256, 0, stream>>>(xtb, Wcat, bias_cat, pos, cam_emb,
                                                 spcb, kvcat16, offs);
    attn_kernel<<<LQ / 2, 256, 0, stream>>>(spcb, kvcat16, offs, posoff, camoff,
                                            g, attn_ob);
    // out0 = LN0(attn @ Wcomb^T + bcomb + xt)
    gemm_ln<<<300, 256, 0, stream>>>(attn_ob, wcombb, bcomb, xt, norm0_g, norm0_b,
                                     out0, out0b);
    // hidden = relu(out0 @ lin1^T + b1)
    gemm_bf16<<<dim3(2, 150), 256, 0, stream>>>(out0b, lin1b, lin1_b, nullptr,
                                                hidden, 256, 1);
    // out_ln = LN2(hidden @ lin2^T + b2 + out0)
    gemm_ln<<<300, 256, 0, stream>>>(hidden, lin2b, lin2_b, out0, norm2_g, norm2_b,
                                     out_ln, nullptr);
    transpose_out<<<tgrid, 256, 0, stream>>>(out_ln, (float*)d_out);
}

// Round 5
// 243.167 us; speedup vs baseline: 1.1121x; 1.1121x over previous
//
#include <hip/hip_runtime.h>
#include <math.h>

typedef unsigned short u16;
typedef unsigned int u32;

#define NCAM 6
#define NHEADS 8
#define NPOINTS 4
#define DD 256
#define HH 20
#define WW 40
#define HWSZ 800
#define LQ 4800
#define HDIM 32

typedef __attribute__((ext_vector_type(8))) short bf16x8;
typedef __attribute__((ext_vector_type(4))) float f32x4;

__device__ __forceinline__ u16 f2b(float x) {
    union { float f; u32 u; } v;
    v.f = x;
    u32 r = (v.u + 0x7FFFu + ((v.u >> 16) & 1u)) >> 16;  // RNE
    return (u16)r;
}
__device__ __forceinline__ float lo2f(u32 u) {
    union { u32 u; float f; } v; v.u = u << 16; return v.f;
}
__device__ __forceinline__ float hi2f(u32 u) {
    union { u32 u; float f; } v; v.u = u & 0xFFFF0000u; return v.f;
}

// ---------------------------------------------------------------------------
// prep1: heterogeneous one-shot prep. Block ranges:
// [0,800)      pos + posb
// [800,1184)   xmean (4 rows/block)
// [1184,2336)  weight bf16 conversions (conv0->Wcat[0:256], offwb, lin1b, lin2b)
// [2336,2560)  wprep4: Wcat rows 256..1151 = (kv|off)@W0 folded, bias_cat
// [2560,2816)  wcomb: conv1@out_w -> wcombb, bcomb
// [2816,2822)  camoff
// [2822,4022)  transpose x -> xtb (bf16)
#define P1_BLOCKS 4022
__global__ __launch_bounds__(256) void prep1(
    const float* __restrict__ x, const float* __restrict__ conv0_w,
    const float* __restrict__ conv0_b, const float* __restrict__ key_w,
    const float* __restrict__ key_b, const float* __restrict__ val_w,
    const float* __restrict__ val_b, const float* __restrict__ off_w,
    const float* __restrict__ off_b, const float* __restrict__ lin1_w,
    const float* __restrict__ lin2_w, const float* __restrict__ conv1_w,
    const float* __restrict__ conv1_b, const float* __restrict__ out_w,
    const float* __restrict__ out_b, const float* __restrict__ cam_emb,
    float* __restrict__ pos, u16* __restrict__ posb, u16* __restrict__ xtb,
    float* __restrict__ mu_x, u16* __restrict__ Wcat, float* __restrict__ bias_cat,
    u16* __restrict__ offwb, u16* __restrict__ lin1b, u16* __restrict__ lin2b,
    u16* __restrict__ wcombb, float* __restrict__ bcomb, float* __restrict__ camoff) {
    int b = blockIdx.x, t = threadIdx.x;
    if (b < 800) {
        int hw = b, d = t;
        int h = hw / WW, w = hw % WW;
        int j = (d & 127) >> 1;
        float dim = powf(10000.0f, (float)j * (1.0f / 64.0f));
        float v;
        if (d < 128) v = (float)(h + 1) / (20.0f + 1e-6f) * (2.0f * (float)M_PI);
        else         v = (float)(w + 1) / (40.0f + 1e-6f) * (2.0f * (float)M_PI);
        float p = v / dim;
        float r = (d & 1) ? cosf(p) : sinf(p);
        pos[hw * DD + d] = r;
        posb[hw * DD + d] = f2b(r);
    } else if (b < 1184) {
        int row = (b - 800) * 4 + (t >> 6);  // 0..1535
        int lane = t & 63;
        const float* base = x + (size_t)row * HWSZ;
        float s = 0.f;
        for (int i = lane; i < HWSZ; i += 64) s += base[i];
#pragma unroll
        for (int m = 1; m <= 32; m <<= 1) s += __shfl_xor(s, m);
        if (lane == 0) mu_x[row] = s * (1.0f / (float)HWSZ);
    } else if (b < 2336) {
        int i = (b - 1184) * 256 + t;  // < 294912
        if (i < 65536) {
            Wcat[i] = f2b(conv0_w[i]);
            if (i < 256) bias_cat[i] = conv0_b[i];
        } else if (i < 163840) {
            offwb[i - 65536] = f2b(off_w[i - 65536]);
        } else if (i < 229376) {
            lin1b[i - 163840] = f2b(lin1_w[i - 163840]);
        } else {
            lin2b[i - 229376] = f2b(lin2_w[i - 229376]);
        }
    } else if (b < 2560) {
        int rbase = 256 + (b - 2336) * 4;
        __shared__ float rowv[4][DD];
        __shared__ float cb[DD];
        cb[t] = conv0_b[t];
#pragma unroll
        for (int j = 0; j < 4; ++j) {
            int row = rbase + j;
            const float* srcp;
            if (row < 768) {
                int rj = row - 256;
                int head = rj >> 6, cpair = (rj >> 1) & 31, kv = rj & 1;
                srcp = (kv ? val_w : key_w) + (size_t)(head * 32 + cpair) * DD;
            } else {
                srcp = off_w + (size_t)(row - 768) * DD;
            }
            rowv[j][t] = srcp[t];
        }
        __syncthreads();
        float acc[4] = {0.f, 0.f, 0.f, 0.f};
        for (int c = 0; c < DD; ++c) {
            float w0 = conv0_w[(size_t)c * DD + t];
#pragma unroll
            for (int j = 0; j < 4; ++j) acc[j] += rowv[j][c] * w0;
        }
#pragma unroll
        for (int j = 0; j < 4; ++j) Wcat[(size_t)(rbase + j) * DD + t] = f2b(acc[j]);
        if (t < 4) {
            int row = rbase + t;
            float bb;
            if (row < 768) {
                int rj = row - 256;
                int head = rj >> 6, cpair = (rj >> 1) & 31, kv = rj & 1;
                bb = (kv ? val_b : key_b)[head * 32 + cpair];
            } else {
                bb = off_b[row - 768];
            }
            for (int c = 0; c < DD; ++c) bb += rowv[t][c] * cb[c];
            bias_cat[row] = bb;
        }
    } else if (b < 2816) {
        int n = b - 2560;
        __shared__ float rowv[DD];
        rowv[t] = conv1_w[(size_t)n * DD + t];
        __syncthreads();
        float acc = 0.f;
        for (int m = 0; m < DD; ++m) acc += rowv[m] * out_w[(size_t)m * DD + t];
        wcombb[(size_t)n * DD + t] = f2b(acc);
        if (t == 0) {
            float bb = conv1_b[n];
            for (int m = 0; m < DD; ++m) bb += rowv[m] * out_b[m];
            bcomb[n] = bb;
        }
    } else if (b < 2822) {
        int cam = b - 2816;
        __shared__ float ce[DD];
        ce[t] = cam_emb[cam * DD + t];
        __syncthreads();
        for (int i = t; i < 384; i += 256) {
            float a = 0.f;
            const float* wr = off_w + (size_t)i * DD;
            for (int c = 0; c < DD; ++c) a += ce[c] * wr[c];
            camoff[cam * 384 + i] = a;
        }
    } else {
        int idx = b - 2822;  // 0..1199
        int cam = idx / 200, rem = idx % 200;
        int hw0 = (rem % 25) * 32, c0 = (rem / 25) * 32;
        __shared__ float tile[32][33];
        int lhw = t & 31, lc4 = t >> 5;
#pragma unroll
        for (int i = 0; i < 4; ++i) {
            int lc = lc4 * 4 + i;
            tile[lc][lhw] = x[((size_t)(cam * DD + c0 + lc)) * HWSZ + hw0 + lhw];
        }
        __syncthreads();
        int lc2 = t & 31, lhw4 = t >> 5;
#pragma unroll
        for (int i = 0; i < 4; ++i) {
            int lhw2 = lhw4 * 4 + i;
            xtb[((size_t)(cam * HWSZ + hw0 + lhw2)) * DD + c0 + lc2] =
                f2b(tile[lc2][lhw2]);
        }
    }
}

// ---------------------------------------------------------------------------
// prep2: blocks [0,75) posoff = pos@off_w^T (bf16 MFMA); [75,81) meang2.
__global__ __launch_bounds__(256) void prep2(
    const u16* __restrict__ posb, const u16* __restrict__ offwb,
    float* __restrict__ posoff, const float* __restrict__ mu_x,
    const float* __restrict__ conv0_w, const float* __restrict__ conv0_b,
    const float* __restrict__ cam_emb, const float* __restrict__ conv2_w,
    const float* __restrict__ conv2_b, float* __restrict__ g) {
    int b = blockIdx.x, t = threadIdx.x;
    if (b < 75) {
        __shared__ __align__(16) u16 As[1056];
        __shared__ __align__(16) u16 Bs[4120];
        int col0 = (b % 3) * 128, row0 = (b / 3) * 32;
        int wv = t >> 6, lane = t & 63;
        int quad = lane >> 4, l = lane & 15;
        f32x4 acc[2][2] = {};
        for (int k0 = 0; k0 < 256; k0 += 32) {
            __syncthreads();
            if (t < 128) {
                int m = t >> 2, j = t & 3;
                *(uint4*)&As[(j * 33 + m) * 8] =
                    *(const uint4*)&posb[(size_t)(row0 + m) * 256 + k0 + j * 8];
            }
            {
                int n = t >> 1, jp = (t & 1) * 2;
                const u16* gsrc = &offwb[(size_t)(col0 + n) * 256 + k0 + jp * 8];
                *(uint4*)&Bs[(jp * 129 + n) * 8]       = *(const uint4*)gsrc;
                *(uint4*)&Bs[((jp + 1) * 129 + n) * 8] = *(const uint4*)(gsrc + 8);
            }
            __syncthreads();
            bf16x8 a0 = *(const bf16x8*)&As[(quad * 33 + l) * 8];
            bf16x8 a1 = *(const bf16x8*)&As[(quad * 33 + 16 + l) * 8];
            bf16x8 b0 = *(const bf16x8*)&Bs[(quad * 129 + wv * 32 + l) * 8];
            bf16x8 b1 = *(const bf16x8*)&Bs[(quad * 129 + wv * 32 + 16 + l) * 8];
            acc[0][0] = __builtin_amdgcn_mfma_f32_16x16x32_bf16(a0, b0, acc[0][0], 0, 0, 0);
            acc[0][1] = __builtin_amdgcn_mfma_f32_16x16x32_bf16(a0, b1, acc[0][1], 0, 0, 0);
            acc[1][0] = __builtin_amdgcn_mfma_f32_16x16x32_bf16(a1, b0, acc[1][0], 0, 0, 0);
            acc[1][1] = __builtin_amdgcn_mfma_f32_16x16x32_bf16(a1, b1, acc[1][1], 0, 0, 0);
        }
#pragma unroll
        for (int mt = 0; mt < 2; ++mt) {
#pragma unroll
            for (int nt = 0; nt < 2; ++nt) {
                int col = col0 + wv * 32 + nt * 16 + l;
#pragma unroll
                for (int r = 0; r < 4; ++r) {
                    int row = row0 + mt * 16 + quad * 4 + r;
                    posoff[(size_t)row * 384 + col] = acc[mt][nt][r];
                }
            }
        }
    } else {
        int cam = b - 75;
        __shared__ float mu[DD];
        __shared__ float smu[DD];
        // analytic pos column-mean: d<128 depends only on h, d>=128 only on w
        float pm;
        {
            int d = t;
            int j = (d & 127) >> 1;
            float inv = 1.0f / powf(10000.0f, (float)j * (1.0f / 64.0f));
            float s = 0.f;
            if (d < 128) {
                for (int h = 0; h < HH; ++h) {
                    float p = (float)(h + 1) / (20.0f + 1e-6f) * (2.0f * (float)M_PI) * inv;
                    s += (d & 1) ? cosf(p) : sinf(p);
                }
                pm = s * (1.0f / (float)HH);
            } else {
                for (int w = 0; w < WW; ++w) {
                    float p = (float)(w + 1) / (40.0f + 1e-6f) * (2.0f * (float)M_PI) * inv;
                    s += (d & 1) ? cosf(p) : sinf(p);
                }
                pm = s * (1.0f / (float)WW);
            }
        }
        mu[t] = mu_x[cam * DD + t];
        __syncthreads();
        float a = conv0_b[t] + pm + cam_emb[cam * DD + t];
        const float* wr = conv0_w + (size_t)t * DD;
        for (int k = 0; k < DD; ++k) a += mu[k] * wr[k];
        smu[t] = a;
        __syncthreads();
        float ga = conv2_b[t];
        const float* w2r = conv2_w + (size_t)t * DD;
        for (int d = 0; d < DD; ++d) ga += smu[d] * w2r[d];
        g[cam * DD + t] = ga;
    }
}

// ---------------------------------------------------------------------------
// bf16 MFMA GEMM (BM=32, BN=128): C = A@W^T (+bias). mode 0: fp32 out, 1: relu bf16
__global__ __launch_bounds__(256) void gemm_bf16(
    const u16* __restrict__ Ab, const u16* __restrict__ Wb,
    const float* __restrict__ bias, float* __restrict__ C,
    u16* __restrict__ Cb, int N, int mode) {
    __shared__ __align__(16) u16 As[1056];
    __shared__ __align__(16) u16 Bs[4120];
    int t = threadIdx.x;
    int col0 = blockIdx.x * 128, row0 = blockIdx.y * 32;
    int wv = t >> 6, lane = t & 63;
    int quad = lane >> 4, l = lane & 15;
    f32x4 acc[2][2] = {};
    for (int k0 = 0; k0 < 256; k0 += 32) {
        __syncthreads();
        if (t < 128) {
            int m = t >> 2, j = t & 3;
            *(uint4*)&As[(j * 33 + m) * 8] =
                *(const uint4*)&Ab[(size_t)(row0 + m) * 256 + k0 + j * 8];
        }
        {
            int n = t >> 1, jp = (t & 1) * 2;
            const u16* gsrc = &Wb[(size_t)(col0 + n) * 256 + k0 + jp * 8];
            *(uint4*)&Bs[(jp * 129 + n) * 8]       = *(const uint4*)gsrc;
            *(uint4*)&Bs[((jp + 1) * 129 + n) * 8] = *(const uint4*)(gsrc + 8);
        }
        __syncthreads();
        bf16x8 a0 = *(const bf16x8*)&As[(quad * 33 + l) * 8];
        bf16x8 a1 = *(const bf16x8*)&As[(quad * 33 + 16 + l) * 8];
        bf16x8 b0 = *(const bf16x8*)&Bs[(quad * 129 + wv * 32 + l) * 8];
        bf16x8 b1 = *(const bf16x8*)&Bs[(quad * 129 + wv * 32 + 16 + l) * 8];
        acc[0][0] = __builtin_amdgcn_mfma_f32_16x16x32_bf16(a0, b0, acc[0][0], 0, 0, 0);
        acc[0][1] = __builtin_amdgcn_mfma_f32_16x16x32_bf16(a0, b1, acc[0][1], 0, 0, 0);
        acc[1][0] = __builtin_amdgcn_mfma_f32_16x16x32_bf16(a1, b0, acc[1][0], 0, 0, 0);
        acc[1][1] = __builtin_amdgcn_mfma_f32_16x16x32_bf16(a1, b1, acc[1][1], 0, 0, 0);
    }
#pragma unroll
    for (int mt = 0; mt < 2; ++mt) {
#pragma unroll
        for (int nt = 0; nt < 2; ++nt) {
            int col = col0 + wv * 32 + nt * 16 + l;
            float bb = bias ? bias[col] : 0.f;
#pragma unroll
            for (int r = 0; r < 4; ++r) {
                int row = row0 + mt * 16 + quad * 4 + r;
                float v = acc[mt][nt][r] + bb;
                size_t oi = (size_t)row * N + col;
                if (mode == 0) C[oi] = v;
                else           Cb[oi] = f2b(fmaxf(v, 0.f));
            }
        }
    }
}

// ---------------------------------------------------------------------------
// Fused N=1152 GEMM on xtb: cols 0..255 conv0->spcb(+pos+cam), 256..767 kv->bf16,
// 768..1151 offsets->fp32
__global__ __launch_bounds__(256) void gemm_fused(
    const u16* __restrict__ Ab, const u16* __restrict__ Wcat,
    const float* __restrict__ bias_cat, const float* __restrict__ pos,
    const float* __restrict__ cam_emb, u16* __restrict__ spcb,
    u16* __restrict__ kvcat16, float* __restrict__ offs) {
    __shared__ __align__(16) u16 As[1056];
    __shared__ __align__(16) u16 Bs[4120];
    int t = threadIdx.x;
    int col0 = blockIdx.x * 128, row0 = blockIdx.y * 32;
    int wv = t >> 6, lane = t & 63;
    int quad = lane >> 4, l = lane & 15;
    f32x4 acc[2][2] = {};
    for (int k0 = 0; k0 < 256; k0 += 32) {
        __syncthreads();
        if (t < 128) {
            int m = t >> 2, j = t & 3;
            *(uint4*)&As[(j * 33 + m) * 8] =
                *(const uint4*)&Ab[(size_t)(row0 + m) * 256 + k0 + j * 8];
        }
        {
            int n = t >> 1, jp = (t & 1) * 2;
            const u16* gsrc = &Wcat[(size_t)(col0 + n) * 256 + k0 + jp * 8];
            *(uint4*)&Bs[(jp * 129 + n) * 8]       = *(const uint4*)gsrc;
            *(uint4*)&Bs[((jp + 1) * 129 + n) * 8] = *(const uint4*)(gsrc + 8);
        }
        __syncthreads();
        bf16x8 a0 = *(const bf16x8*)&As[(quad * 33 + l) * 8];
        bf16x8 a1 = *(const bf16x8*)&As[(quad * 33 + 16 + l) * 8];
        bf16x8 b0 = *(const bf16x8*)&Bs[(quad * 129 + wv * 32 + l) * 8];
        bf16x8 b1 = *(const bf16x8*)&Bs[(quad * 129 + wv * 32 + 16 + l) * 8];
        acc[0][0] = __builtin_amdgcn_mfma_f32_16x16x32_bf16(a0, b0, acc[0][0], 0, 0, 0);
        acc[0][1] = __builtin_amdgcn_mfma_f32_16x16x32_bf16(a0, b1, acc[0][1], 0, 0, 0);
        acc[1][0] = __builtin_amdgcn_mfma_f32_16x16x32_bf16(a1, b0, acc[1][0], 0, 0, 0);
        acc[1][1] = __builtin_amdgcn_mfma_f32_16x16x32_bf16(a1, b1, acc[1][1], 0, 0, 0);
    }
#pragma unroll
    for (int mt = 0; mt < 2; ++mt) {
#pragma unroll
        for (int nt = 0; nt < 2; ++nt) {
            int col = col0 + wv * 32 + nt * 16 + l;
            float bb = bias_cat[col];
#pragma unroll
            for (int r = 0; r < 4; ++r) {
                int row = row0 + mt * 16 + quad * 4 + r;
                float v = acc[mt][nt][r] + bb;
                if (col0 < 256) {
                    int cam = row / HWSZ, hw = row % HWSZ;
                    spcb[(size_t)row * 256 + col] =
                        f2b(v + pos[(size_t)hw * 256 + col] + cam_emb[cam * 256 + col]);
                } else if (col0 < 768) {
                    kvcat16[(size_t)row * 512 + (col - 256)] = f2b(v);
                } else {
                    offs[(size_t)row * 384 + (col - 768)] = v;
                }
            }
        }
    }
}

// ---------------------------------------------------------------------------
// Deformable attention: 2 queries/block, 16 lanes/head (2 channels/lane),
// staged bilinear (weight,index) uint2 pairs, bf16 kv gathers, online softmax.
__global__ __launch_bounds__(256, 6) void attn_kernel(
    const u16* __restrict__ spcb, const u16* __restrict__ kvcat16,
    const float* __restrict__ offs, const float* __restrict__ posoff,
    const float* __restrict__ camoff, const float* __restrict__ g,
    u16* __restrict__ attn_out) {
    int qq = blockIdx.x;
    int q0 = qq * 2;
    int tid = threadIdx.x;
    int cam = q0 / HWSZ;
    int hw0 = q0 % HWSZ;
    __shared__ float soff[2][384];
    __shared__ uint2 widx[2][192][4];
    for (int i = tid; i < 768; i += 256) {
        int qi = i / 384, n = i - qi * 384;
        soff[qi][n] = offs[(size_t)(q0 + qi) * 384 + n] +
                      posoff[(size_t)(hw0 + qi) * 384 + n] + camoff[cam * 384 + n];
    }
    __syncthreads();
    for (int e2 = tid; e2 < 384; e2 += 256) {
        int qi = e2 / 192, e = e2 - qi * 192;
        int head = e / 24, r = e - head * 24;
        int scam = r >> 2;
        int hw = hw0 + qi;
        int h = hw / WW, w = hw - h * WW;
        float X = (float)w + soff[qi][e * 2];
        float Y = (float)h + soff[qi][e * 2 + 1];
        float x0f = floorf(X), y0f = floorf(Y);
        float fx = X - x0f, fy = Y - y0f;
        int x0 = (int)x0f, y0 = (int)y0f, x1 = x0 + 1, y1 = y0 + 1;
        float vx0 = (x0 >= 0 && x0 < WW) ? 1.f : 0.f;
        float vx1 = (x1 >= 0 && x1 < WW) ? 1.f : 0.f;
        float vy0 = (y0 >= 0 && y0 < HH) ? 1.f : 0.f;
        float vy1 = (y1 >= 0 && y1 < HH) ? 1.f : 0.f;
        int cx0 = min(max(x0, 0), WW - 1), cx1 = min(max(x1, 0), WW - 1);
        int cy0 = min(max(y0, 0), HH - 1), cy1 = min(max(y1, 0), HH - 1);
        int pb = scam * HWSZ, hb = head * 64;
        widx[qi][e][0] = make_uint2(__float_as_uint((1.f - fx) * (1.f - fy) * vx0 * vy0),
                                    (u32)(((pb + cy0 * WW + cx0) << 9) + hb));
        widx[qi][e][1] = make_uint2(__float_as_uint(fx * (1.f - fy) * vx1 * vy0),
                                    (u32)(((pb + cy0 * WW + cx1) << 9) + hb));
        widx[qi][e][2] = make_uint2(__float_as_uint((1.f - fx) * fy * vx0 * vy1),
                                    (u32)(((pb + cy1 * WW + cx0) << 9) + hb));
        widx[qi][e][3] = make_uint2(__float_as_uint(fx * fy * vx1 * vy1),
                                    (u32)(((pb + cy1 * WW + cx1) << 9) + hb));
    }
    __syncthreads();
    int qi = tid >> 7, head = (tid >> 4) & 7, l = tid & 15;
    int q = q0 + qi;
    int c0 = l * 2;
    u32 qu = *(const u32*)&spcb[(size_t)q * 256 + head * 32 + c0];
    const float scale = 0.17677669529663687f;  // 1/sqrt(32)
    float q0s = lo2f(qu) * scale, q1s = hi2f(qu) * scale;
    float m = -1e30f, den = 0.f, o0 = 0.f, o1 = 0.f;
    for (int sc = 0; sc < NCAM; ++sc) {
        float av0[4], av1[4], lg[4];
#pragma unroll
        for (int p = 0; p < 4; ++p) {
            int e = head * 24 + sc * 4 + p;
            float ak0 = 0.f, ak1 = 0.f, a0 = 0.f, a1 = 0.f;
#pragma unroll
            for (int j = 0; j < 4; ++j) {
                uint2 wi = widx[qi][e][j];
                float wj = __uint_as_float(wi.x);
                int idx = (int)wi.y + 4 * l;
                uint2 d = *(const uint2*)&kvcat16[idx];  // k0,v0,k1,v1
                ak0 += wj * lo2f(d.x);
                a0  += wj * hi2f(d.x);
                ak1 += wj * lo2f(d.y);
                a1  += wj * hi2f(d.y);
            }
            av0[p] = a0; av1[p] = a1;
            float pl = q0s * ak0 + q1s * ak1;
            pl += __shfl_xor(pl, 1);
            pl += __shfl_xor(pl, 2);
            pl += __shfl_xor(pl, 4);
            pl += __shfl_xor(pl, 8);
            lg[p] = pl;
        }
        float2 gv = *(const float2*)&g[sc * 256 + head * 32 + c0];
        float pg = q0s * gv.x + q1s * gv.y;
        pg += __shfl_xor(pg, 1);
        pg += __shfl_xor(pg, 2);
        pg += __shfl_xor(pg, 4);
        pg += __shfl_xor(pg, 8);
        float mc = fmaxf(fmaxf(fmaxf(lg[0], lg[1]), fmaxf(lg[2], lg[3])), pg);
        float mn = fmaxf(m, mc);
        float aa = __expf(m - mn);
        float e0p = __expf(lg[0] - mn), e1p = __expf(lg[1] - mn);
        float e2p = __expf(lg[2] - mn), e3p = __expf(lg[3] - mn);
        float e4p = __expf(pg - mn);
        den = den * aa + (e0p + e1p + e2p + e3p + e4p);
        o0 = o0 * aa + e0p * av0[0] + e1p * av0[1] + e2p * av0[2] + e3p * av0[3] + e4p * gv.x;
        o1 = o1 * aa + e0p * av1[0] + e1p * av1[1] + e2p * av1[2] + e3p * av1[3] + e4p * gv.y;
        m = mn;
    }
    float inv = 1.f / den;
    u32 pack = (u32)f2b(o0 * inv) | ((u32)f2b(o1 * inv) << 16);
    *(u32*)&attn_out[(size_t)q * 256 + head * 32 + c0] = pack;
}

// ---------------------------------------------------------------------------
// Fused GEMM (N=256) + residual + LayerNorm. BM=16, grid 300.
// residual: e0_rm (row-major) or x_nchw (direct NCHW, float4).
// store: C_rm (+Cb bf16) or C_nchw (transposed NCHW, float4) -> d_out.
__global__ __launch_bounds__(256) void gemm_ln(
    const u16* __restrict__ Ab, const u16* __restrict__ Wb,
    const float* __restrict__ bias, const float* __restrict__ e0_rm,
    const float* __restrict__ x_nchw, const float* __restrict__ gamma,
    const float* __restrict__ beta, float* __restrict__ C_rm,
    u16* __restrict__ Cb, float* __restrict__ C_nchw) {
    __shared__ __align__(16) u16 As[552];
    __shared__ __align__(16) u16 Bs[8232];
    __shared__ float red[4][4][4][2];
    int t = threadIdx.x;
    int row0 = blockIdx.x * 16;
    int wv = t >> 6, lane = t & 63, quad = lane >> 4, l = lane & 15;
    f32x4 acc[4] = {};
    for (int k0 = 0; k0 < 256; k0 += 32) {
        __syncthreads();
        if (t < 64) {
            int mm = t >> 2, j = t & 3;
            *(uint4*)&As[(j * 17 + mm) * 8] =
                *(const uint4*)&Ab[(size_t)(row0 + mm) * 256 + k0 + j * 8];
        }
#pragma unroll
        for (int j = 0; j < 4; ++j)
            *(uint4*)&Bs[(j * 257 + t) * 8] =
                *(const uint4*)&Wb[(size_t)t * 256 + k0 + j * 8];
        __syncthreads();
        bf16x8 a = *(const bf16x8*)&As[(quad * 17 + l) * 8];
#pragma unroll
        for (int nt = 0; nt < 4; ++nt) {
            bf16x8 b = *(const bf16x8*)&Bs[(quad * 257 + wv * 64 + nt * 16 + l) * 8];
            acc[nt] = __builtin_amdgcn_mfma_f32_16x16x32_bf16(a, b, acc[nt], 0, 0, 0);
        }
    }
    int cam = row0 / HWSZ;
    int hw0q = row0 % HWSZ + quad * 4;
    float v[4][4];
    float g4[4], b4[4];
#pragma unroll
    for (int nt = 0; nt < 4; ++nt) {
        int col = wv * 64 + nt * 16 + l;
        float bb = bias[col];
        g4[nt] = gamma[col];
        b4[nt] = beta[col];
        if (x_nchw) {
            float4 rx = *(const float4*)&x_nchw[((size_t)(cam * 256 + col)) * HWSZ + hw0q];
            v[nt][0] = acc[nt][0] + bb + rx.x;
            v[nt][1] = acc[nt][1] + bb + rx.y;
            v[nt][2] = acc[nt][2] + bb + rx.z;
            v[nt][3] = acc[nt][3] + bb + rx.w;
        } else {
#pragma unroll
            for (int r = 0; r < 4; ++r) {
                int row = row0 + quad * 4 + r;
                v[nt][r] = acc[nt][r] + bb + e0_rm[(size_t)row * 256 + col];
            }
        }
    }
#pragma unroll
    for (int r = 0; r < 4; ++r) {
        float s = v[0][r] + v[1][r] + v[2][r] + v[3][r];
        float sq = v[0][r] * v[0][r] + v[1][r] * v[1][r] +
                   v[2][r] * v[2][r] + v[3][r] * v[3][r];
#pragma unroll
        for (int msk = 1; msk <= 8; msk <<= 1) {
            s += __shfl_xor(s, msk);
            sq += __shfl_xor(sq, msk);
        }
        if (l == 0) { red[wv][quad][r][0] = s; red[wv][quad][r][1] = sq; }
    }
    __syncthreads();
    float mean[4], rstd[4];
#pragma unroll
    for (int r = 0; r < 4; ++r) {
        float S = red[0][quad][r][0] + red[1][quad][r][0] +
                  red[2][quad][r][0] + red[3][quad][r][0];
        float Q = red[0][quad][r][1] + red[1][quad][r][1] +
                  red[2][quad][r][1] + red[3][quad][r][1];
        mean[r] = S * (1.0f / 256.0f);
        float var = Q * (1.0f / 256.0f) - mean[r] * mean[r];
        rstd[r] = rsqrtf(var + 1e-5f);
    }
#pragma unroll
    for (int nt = 0; nt < 4; ++nt) {
        int col = wv * 64 + nt * 16 + l;
        if (C_nchw) {
            float4 ov4;
            ov4.x = (v[nt][0] - mean[0]) * rstd[0] * g4[nt] + b4[nt];
            ov4.y = (v[nt][1] - mean[1]) * rstd[1] * g4[nt] + b4[nt];
            ov4.z = (v[nt][2] - mean[2]) * rstd[2] * g4[nt] + b4[nt];
            ov4.w = (v[nt][3] - mean[3]) * rstd[3] * g4[nt] + b4[nt];
            *(float4*)&C_nchw[((size_t)(cam * 256 + col)) * HWSZ + hw0q] = ov4;
        } else {
#pragma unroll
            for (int r = 0; r < 4; ++r) {
                int row = row0 + quad * 4 + r;
                float ov = (v[nt][r] - mean[r]) * rstd[r] * g4[nt] + b4[nt];
                C_rm[(size_t)row * 256 + col] = ov;
                if (Cb) Cb[(size_t)row * 256 + col] = f2b(ov);
            }
        }
    }
}

// ---------------------------------------------------------------------------
extern "C" void kernel_launch(void* const* d_in, const int* in_sizes, int n_in,
                              void* d_out, int out_size, void* d_ws, size_t ws_size,
                              hipStream_t stream) {
    const float* x       = (const float*)d_in[0];
    const float* conv0_w = (const float*)d_in[1];
    const float* conv0_b = (const float*)d_in[2];
    const float* conv2_w = (const float*)d_in[3];
    const float* conv2_b = (const float*)d_in[4];
    const float* cam_emb = (const float*)d_in[5];
    const float* off_w   = (const float*)d_in[6];
    const float* off_b   = (const float*)d_in[7];
    const float* val_w   = (const float*)d_in[8];
    const float* val_b   = (const float*)d_in[9];
    const float* key_w   = (const float*)d_in[10];
    const float* key_b   = (const float*)d_in[11];
    const float* out_w   = (const float*)d_in[12];
    const float* out_b   = (const float*)d_in[13];
    const float* conv1_w = (const float*)d_in[14];
    const float* conv1_b = (const float*)d_in[15];
    const float* norm0_g = (const float*)d_in[16];
    const float* norm0_b = (const float*)d_in[17];
    const float* lin1_w  = (const float*)d_in[18];
    const float* lin1_b  = (const float*)d_in[19];
    const float* lin2_w  = (const float*)d_in[20];
    const float* lin2_b  = (const float*)d_in[21];
    const float* norm2_g = (const float*)d_in[22];
    const float* norm2_b = (const float*)d_in[23];

    float* ws = (float*)d_ws;
    const size_t SZ = (size_t)LQ * DD;  // 1,228,800
    float* pos      = ws;                       // 204800
    float* mu_x     = pos + 204800;             // 1536
    float* g        = mu_x + 1536;              // 1536
    float* camoff   = g + 1536;                 // 2304
    float* posoff   = camoff + 2304;            // 307200
    float* bias_cat = posoff + 307200;          // 1152
    float* bcomb    = bias_cat + 1152;          // 256
    float* offs     = bcomb + 256;              // 1843200 (alias: out0 + out0b)
    float* f_posb   = offs + 1843200;           // 102400
    float* f_xtb    = f_posb + 102400;          // 614400 (alias: attn_ob)
    float* f_spcb   = f_xtb + 614400;           // 614400
    float* f_kvcat  = f_spcb + 614400;          // 1228800 (alias: hidden)
    float* f_Wcat   = f_kvcat + 1228800;        // 147456
    float* f_offwb  = f_Wcat + 147456;          // 49152
    float* f_lin1b  = f_offwb + 49152;          // 32768
    float* f_lin2b  = f_lin1b + 32768;          // 32768
    float* f_wcombb = f_lin2b + 32768;          // 32768

    u16* posb    = (u16*)f_posb;
    u16* xtb     = (u16*)f_xtb;
    u16* spcb    = (u16*)f_spcb;
    u16* kvcat16 = (u16*)f_kvcat;
    u16* Wcat    = (u16*)f_Wcat;
    u16* offwb   = (u16*)f_offwb;
    u16* lin1b   = (u16*)f_lin1b;
    u16* lin2b   = (u16*)f_lin2b;
    u16* wcombb  = (u16*)f_wcombb;
    // aliases (disjoint lifetimes)
    u16*   attn_ob = xtb;                 // xtb dead after gemm_fused
    float* out0    = offs;                // offs dead after attn
    u16*   out0b   = (u16*)(offs + SZ);
    u16*   hidden  = kvcat16;             // kvcat dead after attn

    prep1<<<P1_BLOCKS, 256, 0, stream>>>(
        x, conv0_w, conv0_b, key_w, key_b, val_w, val_b, off_w, off_b,
        lin1_w, lin2_w, conv1_w, conv1_b, out_w, out_b, cam_emb,
        pos, posb, xtb, mu_x, Wcat, bias_cat, offwb, lin1b, lin2b,
        wcombb, bcomb, camoff);
    prep2<<<81, 256, 0, stream>>>(posb, offwb, posoff, mu_x, conv0_w, conv0_b,
                                  cam_emb, conv2_w, conv2_b, g);
    gemm_fused<<<dim3(9, 150), 256, 0, stream>>>(xtb, Wcat, bias_cat, pos, cam_emb,
                                                 spcb, kvcat16, offs);
    attn_kernel<<<LQ / 2, 256, 0, stream>>>(spcb, kvcat16, offs, posoff, camoff,
                                            g, attn_ob);
    // out0 = LN0(attn @ Wcomb^T + bcomb + x_residual)  [+ bf16 copy]
    gemm_ln<<<300, 256, 0, stream>>>(attn_ob, wcombb, bcomb, nullptr, x,
                                     norm0_g, norm0_b, out0, out0b, nullptr);
    // hidden = relu(out0 @ lin1^T + b1)
    gemm_bf16<<<dim3(2, 150), 256, 0, stream>>>(out0b, lin1b, lin1_b, nullptr,
                                                hidden, 256, 1);
    // d_out = LN2(hidden @ lin2^T + b2 + out0), stored NCHW directly
    gemm_ln<<<300, 256, 0, stream>>>(hidden, lin2b, lin2_b, out0, nullptr,
                                     norm2_g, norm2_b, nullptr, nullptr,
                                     (float*)d_out);
}

// Round 6
// 220.320 us; speedup vs baseline: 1.2275x; 1.1037x over previous
//
#include <hip/hip_runtime.h>
#include <math.h>

typedef unsigned short u16;
typedef unsigned int u32;

#define NCAM 6
#define NHEADS 8
#define NPOINTS 4
#define DD 256
#define HH 20
#define WW 40
#define HWSZ 800
#define LQ 4800
#define HDIM 32

typedef __attribute__((ext_vector_type(8))) short bf16x8;
typedef __attribute__((ext_vector_type(4))) float f32x4;

__device__ __forceinline__ u16 f2b(float x) {
    union { float f; u32 u; } v;
    v.f = x;
    u32 r = (v.u + 0x7FFFu + ((v.u >> 16) & 1u)) >> 16;  // RNE
    return (u16)r;
}
__device__ __forceinline__ float lo2f(u32 u) {
    union { u32 u; float f; } v; v.u = u << 16; return v.f;
}
__device__ __forceinline__ float hi2f(u32 u) {
    union { u32 u; float f; } v; v.u = u & 0xFFFF0000u; return v.f;
}

// ---------------------------------------------------------------------------
// prep1: heterogeneous one-shot prep. Block ranges:
// [0,800)      pos fp32
// [800,1184)   xmean (4 rows/block)
// [1184,1952)  weight bf16 conversions (conv0->Wcat[0:256]+bias, lin1b, lin2b)
// [1952,2176)  wprep4: Wcat rows 256..1151 = (kv|off)@W0 folded, bias_cat
// [2176,2432)  wcomb: conv1@out_w -> wcombb, bcomb
// [2432,2438)  camoff
// [2438,2498)  posy[20][384] / posx[40][384] tables (pos@off_w^T split)
// [2498,3698)  transpose x -> xtb (bf16)
#define P1_BLOCKS 3698
__global__ __launch_bounds__(256) void prep1(
    const float* __restrict__ x, const float* __restrict__ conv0_w,
    const float* __restrict__ conv0_b, const float* __restrict__ key_w,
    const float* __restrict__ key_b, const float* __restrict__ val_w,
    const float* __restrict__ val_b, const float* __restrict__ off_w,
    const float* __restrict__ off_b, const float* __restrict__ lin1_w,
    const float* __restrict__ lin2_w, const float* __restrict__ conv1_w,
    const float* __restrict__ conv1_b, const float* __restrict__ out_w,
    const float* __restrict__ out_b, const float* __restrict__ cam_emb,
    float* __restrict__ pos, u16* __restrict__ xtb, float* __restrict__ mu_x,
    u16* __restrict__ Wcat, float* __restrict__ bias_cat,
    u16* __restrict__ lin1b, u16* __restrict__ lin2b,
    u16* __restrict__ wcombb, float* __restrict__ bcomb,
    float* __restrict__ camoff, float* __restrict__ posy,
    float* __restrict__ posx) {
    int b = blockIdx.x, t = threadIdx.x;
    if (b < 800) {
        int hw = b, d = t;
        int h = hw / WW, w = hw % WW;
        int j = (d & 127) >> 1;
        float dim = powf(10000.0f, (float)j * (1.0f / 64.0f));
        float v;
        if (d < 128) v = (float)(h + 1) / (20.0f + 1e-6f) * (2.0f * (float)M_PI);
        else         v = (float)(w + 1) / (40.0f + 1e-6f) * (2.0f * (float)M_PI);
        float p = v / dim;
        pos[hw * DD + d] = (d & 1) ? cosf(p) : sinf(p);
    } else if (b < 1184) {
        int row = (b - 800) * 4 + (t >> 6);  // 0..1535
        int lane = t & 63;
        const float* base = x + (size_t)row * HWSZ;
        float s = 0.f;
        for (int i = lane; i < HWSZ; i += 64) s += base[i];
#pragma unroll
        for (int m = 1; m <= 32; m <<= 1) s += __shfl_xor(s, m);
        if (lane == 0) mu_x[row] = s * (1.0f / (float)HWSZ);
    } else if (b < 1952) {
        int i = (b - 1184) * 256 + t;  // < 196608
        if (i < 65536) {
            Wcat[i] = f2b(conv0_w[i]);
            if (i < 256) bias_cat[i] = conv0_b[i];
        } else if (i < 131072) {
            lin1b[i - 65536] = f2b(lin1_w[i - 65536]);
        } else {
            lin2b[i - 131072] = f2b(lin2_w[i - 131072]);
        }
    } else if (b < 2176) {
        int rbase = 256 + (b - 1952) * 4;
        __shared__ float rowv[4][DD];
        __shared__ float cb[DD];
        cb[t] = conv0_b[t];
#pragma unroll
        for (int j = 0; j < 4; ++j) {
            int row = rbase + j;
            const float* srcp;
            if (row < 768) {
                int rj = row - 256;
                int head = rj >> 6, cpair = (rj >> 1) & 31, kv = rj & 1;
                srcp = (kv ? val_w : key_w) + (size_t)(head * 32 + cpair) * DD;
            } else {
                srcp = off_w + (size_t)(row - 768) * DD;
            }
            rowv[j][t] = srcp[t];
        }
        __syncthreads();
        float acc[4] = {0.f, 0.f, 0.f, 0.f};
        for (int c = 0; c < DD; ++c) {
            float w0 = conv0_w[(size_t)c * DD + t];
#pragma unroll
            for (int j = 0; j < 4; ++j) acc[j] += rowv[j][c] * w0;
        }
#pragma unroll
        for (int j = 0; j < 4; ++j) Wcat[(size_t)(rbase + j) * DD + t] = f2b(acc[j]);
        if (t < 4) {
            int row = rbase + t;
            float bb;
            if (row < 768) {
                int rj = row - 256;
                int head = rj >> 6, cpair = (rj >> 1) & 31, kv = rj & 1;
                bb = (kv ? val_b : key_b)[head * 32 + cpair];
            } else {
                bb = off_b[row - 768];
            }
            for (int c = 0; c < DD; ++c) bb += rowv[t][c] * cb[c];
            bias_cat[row] = bb;
        }
    } else if (b < 2432) {
        int n = b - 2176;
        __shared__ float rowv[DD];
        rowv[t] = conv1_w[(size_t)n * DD + t];
        __syncthreads();
        float acc = 0.f;
        for (int m = 0; m < DD; ++m) acc += rowv[m] * out_w[(size_t)m * DD + t];
        wcombb[(size_t)n * DD + t] = f2b(acc);
        if (t == 0) {
            float bb = conv1_b[n];
            for (int m = 0; m < DD; ++m) bb += rowv[m] * out_b[m];
            bcomb[n] = bb;
        }
    } else if (b < 2438) {
        int cam = b - 2432;
        __shared__ float ce[DD];
        ce[t] = cam_emb[cam * DD + t];
        __syncthreads();
        for (int i = t; i < 384; i += 256) {
            float a = 0.f;
            const float* wr = off_w + (size_t)i * DD;
            for (int c = 0; c < DD; ++c) a += ce[c] * wr[c];
            camoff[cam * 384 + i] = a;
        }
    } else if (b < 2498) {
        // posy[h][n] = py(h) . off_w[n][0:128] ; posx[w][n] = px(w) . off_w[n][128:256]
        int idx = b - 2438;  // 0..59
        __shared__ float pv[128];
        int yside = (idx < 20);
        int coord = yside ? idx : idx - 20;
        if (t < 128) {
            int d = t, j = d >> 1;
            float dim = powf(10000.0f, (float)j * (1.0f / 64.0f));
            float v = yside
                ? (float)(coord + 1) / (20.0f + 1e-6f) * (2.0f * (float)M_PI)
                : (float)(coord + 1) / (40.0f + 1e-6f) * (2.0f * (float)M_PI);
            float p = v / dim;
            pv[d] = (d & 1) ? cosf(p) : sinf(p);
        }
        __syncthreads();
        int koff = yside ? 0 : 128;
        float* outp = yside ? (posy + coord * 384) : (posx + coord * 384);
        for (int n = t; n < 384; n += 256) {
            const float* wr = off_w + (size_t)n * DD + koff;
            float a = 0.f;
            for (int d = 0; d < 128; ++d) a += pv[d] * wr[d];
            outp[n] = a;
        }
    } else {
        int idx = b - 2498;  // 0..1199
        int cam = idx / 200, rem = idx % 200;
        int hw0 = (rem % 25) * 32, c0 = (rem / 25) * 32;
        __shared__ float tile[32][33];
        int lhw = t & 31, lc4 = t >> 5;
#pragma unroll
        for (int i = 0; i < 4; ++i) {
            int lc = lc4 * 4 + i;
            tile[lc][lhw] = x[((size_t)(cam * DD + c0 + lc)) * HWSZ + hw0 + lhw];
        }
        __syncthreads();
        int lc2 = t & 31, lhw4 = t >> 5;
#pragma unroll
        for (int i = 0; i < 4; ++i) {
            int lhw2 = lhw4 * 4 + i;
            xtb[((size_t)(cam * HWSZ + hw0 + lhw2)) * DD + c0 + lc2] =
                f2b(tile[lc2][lhw2]);
        }
    }
}

// ---------------------------------------------------------------------------
// gemm_fused: blocks [0,1350) N=1152 GEMM on xtb (conv0->spcb, kv->bf16,
// off->fp32); blocks [1350,1356) meang (g per cam).
__global__ __launch_bounds__(256) void gemm_fused(
    const u16* __restrict__ Ab, const u16* __restrict__ Wcat,
    const float* __restrict__ bias_cat, const float* __restrict__ pos,
    const float* __restrict__ cam_emb, u16* __restrict__ spcb,
    u16* __restrict__ kvcat16, float* __restrict__ offs,
    const float* __restrict__ mu_x, const float* __restrict__ conv0_w,
    const float* __restrict__ conv0_b, const float* __restrict__ conv2_w,
    const float* __restrict__ conv2_b, float* __restrict__ g) {
    int b = blockIdx.x, t = threadIdx.x;
    if (b < 1350) {
        __shared__ __align__(16) u16 As[1056];
        __shared__ __align__(16) u16 Bs[4120];
        int col0 = (b % 9) * 128, row0 = (b / 9) * 32;
        int wv = t >> 6, lane = t & 63;
        int quad = lane >> 4, l = lane & 15;
        f32x4 acc[2][2] = {};
        for (int k0 = 0; k0 < 256; k0 += 32) {
            __syncthreads();
            if (t < 128) {
                int m = t >> 2, j = t & 3;
                *(uint4*)&As[(j * 33 + m) * 8] =
                    *(const uint4*)&Ab[(size_t)(row0 + m) * 256 + k0 + j * 8];
            }
            {
                int n = t >> 1, jp = (t & 1) * 2;
                const u16* gsrc = &Wcat[(size_t)(col0 + n) * 256 + k0 + jp * 8];
                *(uint4*)&Bs[(jp * 129 + n) * 8]       = *(const uint4*)gsrc;
                *(uint4*)&Bs[((jp + 1) * 129 + n) * 8] = *(const uint4*)(gsrc + 8);
            }
            __syncthreads();
            bf16x8 a0 = *(const bf16x8*)&As[(quad * 33 + l) * 8];
            bf16x8 a1 = *(const bf16x8*)&As[(quad * 33 + 16 + l) * 8];
            bf16x8 b0 = *(const bf16x8*)&Bs[(quad * 129 + wv * 32 + l) * 8];
            bf16x8 b1 = *(const bf16x8*)&Bs[(quad * 129 + wv * 32 + 16 + l) * 8];
            acc[0][0] = __builtin_amdgcn_mfma_f32_16x16x32_bf16(a0, b0, acc[0][0], 0, 0, 0);
            acc[0][1] = __builtin_amdgcn_mfma_f32_16x16x32_bf16(a0, b1, acc[0][1], 0, 0, 0);
            acc[1][0] = __builtin_amdgcn_mfma_f32_16x16x32_bf16(a1, b0, acc[1][0], 0, 0, 0);
            acc[1][1] = __builtin_amdgcn_mfma_f32_16x16x32_bf16(a1, b1, acc[1][1], 0, 0, 0);
        }
#pragma unroll
        for (int mt = 0; mt < 2; ++mt) {
#pragma unroll
            for (int nt = 0; nt < 2; ++nt) {
                int col = col0 + wv * 32 + nt * 16 + l;
                float bb = bias_cat[col];
#pragma unroll
                for (int r = 0; r < 4; ++r) {
                    int row = row0 + mt * 16 + quad * 4 + r;
                    float v = acc[mt][nt][r] + bb;
                    if (col0 < 256) {
                        int cam = row / HWSZ, hw = row % HWSZ;
                        spcb[(size_t)row * 256 + col] =
                            f2b(v + pos[(size_t)hw * 256 + col] + cam_emb[cam * 256 + col]);
                    } else if (col0 < 768) {
                        kvcat16[(size_t)row * 512 + (col - 256)] = f2b(v);
                    } else {
                        offs[(size_t)row * 384 + (col - 768)] = v;
                    }
                }
            }
        }
    } else {
        int cam = b - 1350;
        __shared__ float mu[DD];
        __shared__ float smu[DD];
        float pm;
        {
            int d = t;
            int j = (d & 127) >> 1;
            float inv = 1.0f / powf(10000.0f, (float)j * (1.0f / 64.0f));
            float s = 0.f;
            if (d < 128) {
                for (int h = 0; h < HH; ++h) {
                    float p = (float)(h + 1) / (20.0f + 1e-6f) * (2.0f * (float)M_PI) * inv;
                    s += (d & 1) ? cosf(p) : sinf(p);
                }
                pm = s * (1.0f / (float)HH);
            } else {
                for (int w = 0; w < WW; ++w) {
                    float p = (float)(w + 1) / (40.0f + 1e-6f) * (2.0f * (float)M_PI) * inv;
                    s += (d & 1) ? cosf(p) : sinf(p);
                }
                pm = s * (1.0f / (float)WW);
            }
        }
        mu[t] = mu_x[cam * DD + t];
        __syncthreads();
        float a = conv0_b[t] + pm + cam_emb[cam * DD + t];
        const float* wr = conv0_w + (size_t)t * DD;
        for (int k = 0; k < DD; ++k) a += mu[k] * wr[k];
        smu[t] = a;
        __syncthreads();
        float ga = conv2_b[t];
        const float* w2r = conv2_w + (size_t)t * DD;
        for (int d = 0; d < DD; ++d) ga += smu[d] * w2r[d];
        g[cam * DD + t] = ga;
    }
}

// ---------------------------------------------------------------------------
// Deformable attention: 2 queries/block, 16 lanes/head (2 channels/lane),
// staged bilinear weights/indices (separate 4B arrays: zero bank conflicts),
// bf16 kv gathers, batched online softmax. posoff = posy[h] + posx[w].
__global__ __launch_bounds__(256, 6) void attn_kernel(
    const u16* __restrict__ spcb, const u16* __restrict__ kvcat16,
    const float* __restrict__ offs, const float* __restrict__ posy,
    const float* __restrict__ posx, const float* __restrict__ camoff,
    const float* __restrict__ g, u16* __restrict__ attn_out) {
    int qq = blockIdx.x;
    int q0 = qq * 2;
    int tid = threadIdx.x;
    int cam = q0 / HWSZ;
    int hw0 = q0 % HWSZ;
    __shared__ float soff[2][384];
    __shared__ float wgt[2][192][4];
    __shared__ int   idxp[2][192][4];
    for (int i = tid; i < 768; i += 256) {
        int qi = i / 384, n = i - qi * 384;
        int hw = hw0 + qi;
        int h = hw / WW, w = hw - h * WW;
        soff[qi][n] = offs[(size_t)(q0 + qi) * 384 + n] + posy[h * 384 + n] +
                      posx[w * 384 + n] + camoff[cam * 384 + n];
    }
    __syncthreads();
    for (int e2 = tid; e2 < 384; e2 += 256) {
        int qi = e2 / 192, e = e2 - qi * 192;
        int head = e / 24, r = e - head * 24;
        int scam = r >> 2;
        int hw = hw0 + qi;
        int h = hw / WW, w = hw - h * WW;
        float X = (float)w + soff[qi][e * 2];
        float Y = (float)h + soff[qi][e * 2 + 1];
        float x0f = floorf(X), y0f = floorf(Y);
        float fx = X - x0f, fy = Y - y0f;
        int x0 = (int)x0f, y0 = (int)y0f, x1 = x0 + 1, y1 = y0 + 1;
        float vx0 = (x0 >= 0 && x0 < WW) ? 1.f : 0.f;
        float vx1 = (x1 >= 0 && x1 < WW) ? 1.f : 0.f;
        float vy0 = (y0 >= 0 && y0 < HH) ? 1.f : 0.f;
        float vy1 = (y1 >= 0 && y1 < HH) ? 1.f : 0.f;
        int cx0 = min(max(x0, 0), WW - 1), cx1 = min(max(x1, 0), WW - 1);
        int cy0 = min(max(y0, 0), HH - 1), cy1 = min(max(y1, 0), HH - 1);
        wgt[qi][e][0] = (1.f - fx) * (1.f - fy) * vx0 * vy0;
        wgt[qi][e][1] = fx * (1.f - fy) * vx1 * vy0;
        wgt[qi][e][2] = (1.f - fx) * fy * vx0 * vy1;
        wgt[qi][e][3] = fx * fy * vx1 * vy1;
        int pb = scam * HWSZ, hb = head * 64;
        idxp[qi][e][0] = ((pb + cy0 * WW + cx0) << 9) + hb;
        idxp[qi][e][1] = ((pb + cy0 * WW + cx1) << 9) + hb;
        idxp[qi][e][2] = ((pb + cy1 * WW + cx0) << 9) + hb;
        idxp[qi][e][3] = ((pb + cy1 * WW + cx1) << 9) + hb;
    }
    __syncthreads();
    int qi = tid >> 7, head = (tid >> 4) & 7, l = tid & 15;
    int q = q0 + qi;
    int c0 = l * 2;
    u32 qu = *(const u32*)&spcb[(size_t)q * 256 + head * 32 + c0];
    const float scale = 0.17677669529663687f;  // 1/sqrt(32)
    float q0s = lo2f(qu) * scale, q1s = hi2f(qu) * scale;
    float m = -1e30f, den = 0.f, o0 = 0.f, o1 = 0.f;
    for (int sc = 0; sc < NCAM; ++sc) {
        float av0[4], av1[4], lg[4];
#pragma unroll
        for (int p = 0; p < 4; ++p) {
            int e = head * 24 + sc * 4 + p;
            float ak0 = 0.f, ak1 = 0.f, a0 = 0.f, a1 = 0.f;
#pragma unroll
            for (int j = 0; j < 4; ++j) {
                float wj = wgt[qi][e][j];
                int idx = idxp[qi][e][j] + 4 * l;
                uint2 d = *(const uint2*)&kvcat16[idx];  // k0,v0,k1,v1
                ak0 += wj * lo2f(d.x);
                a0  += wj * hi2f(d.x);
                ak1 += wj * lo2f(d.y);
                a1  += wj * hi2f(d.y);
            }
            av0[p] = a0; av1[p] = a1;
            float pl = q0s * ak0 + q1s * ak1;
            pl += __shfl_xor(pl, 1);
            pl += __shfl_xor(pl, 2);
            pl += __shfl_xor(pl, 4);
            pl += __shfl_xor(pl, 8);
            lg[p] = pl;
        }
        float2 gv = *(const float2*)&g[sc * 256 + head * 32 + c0];
        float pg = q0s * gv.x + q1s * gv.y;
        pg += __shfl_xor(pg, 1);
        pg += __shfl_xor(pg, 2);
        pg += __shfl_xor(pg, 4);
        pg += __shfl_xor(pg, 8);
        float mc = fmaxf(fmaxf(fmaxf(lg[0], lg[1]), fmaxf(lg[2], lg[3])), pg);
        float mn = fmaxf(m, mc);
        float aa = __expf(m - mn);
        float e0p = __expf(lg[0] - mn), e1p = __expf(lg[1] - mn);
        float e2p = __expf(lg[2] - mn), e3p = __expf(lg[3] - mn);
        float e4p = __expf(pg - mn);
        den = den * aa + (e0p + e1p + e2p + e3p + e4p);
        o0 = o0 * aa + e0p * av0[0] + e1p * av0[1] + e2p * av0[2] + e3p * av0[3] + e4p * gv.x;
        o1 = o1 * aa + e0p * av1[0] + e1p * av1[1] + e2p * av1[2] + e3p * av1[3] + e4p * gv.y;
        m = mn;
    }
    float inv = 1.f / den;
    u32 pack = (u32)f2b(o0 * inv) | ((u32)f2b(o1 * inv) << 16);
    *(u32*)&attn_out[(size_t)q * 256 + head * 32 + c0] = pack;
}

// ---------------------------------------------------------------------------
// Mega-epilogue (grid 300, 16 rows/block): everything after attention.
// v  = attn@Wcomb + bcomb + x  -> LN0 -> o0 (regs, fp32) + bf16 to A2(LDS)
// h  = relu(o0b@lin1 + b1)     -> bf16 to A2
// v2 = h@lin2 + b2 + o0        -> LN2 -> d_out (NCHW, float4)
__global__ __launch_bounds__(256) void epilogue(
    const u16* __restrict__ Ab, const u16* __restrict__ Wc,
    const float* __restrict__ bcomb, const float* __restrict__ x_nchw,
    const float* __restrict__ n0g, const float* __restrict__ n0b,
    const u16* __restrict__ W1, const float* __restrict__ b1v,
    const u16* __restrict__ W2, const float* __restrict__ b2v,
    const float* __restrict__ n2g, const float* __restrict__ n2b,
    float* __restrict__ out_nchw) {
    __shared__ __align__(16) u16 As[552];
    __shared__ __align__(16) u16 Bs[8232];
    __shared__ __align__(16) u16 A2[4360];   // [j<32][17 rows][8], 16 rows used
    __shared__ float red[4][4][4][2];
    int t = threadIdx.x;
    int row0 = blockIdx.x * 16;
    int wv = t >> 6, lane = t & 63, quad = lane >> 4, l = lane & 15;
    int cam = row0 / HWSZ;
    int hw0q = row0 % HWSZ + quad * 4;

    // ---- GEMM1: comb (A streamed from global) ----
    f32x4 acc[4] = {};
    for (int k0 = 0; k0 < 256; k0 += 32) {
        __syncthreads();
        if (t < 64) {
            int mm = t >> 2, j = t & 3;
            *(uint4*)&As[(j * 17 + mm) * 8] =
                *(const uint4*)&Ab[(size_t)(row0 + mm) * 256 + k0 + j * 8];
        }
#pragma unroll
        for (int j = 0; j < 4; ++j)
            *(uint4*)&Bs[(j * 257 + t) * 8] =
                *(const uint4*)&Wc[(size_t)t * 256 + k0 + j * 8];
        __syncthreads();
        bf16x8 a = *(const bf16x8*)&As[(quad * 17 + l) * 8];
#pragma unroll
        for (int nt = 0; nt < 4; ++nt) {
            bf16x8 b = *(const bf16x8*)&Bs[(quad * 257 + wv * 64 + nt * 16 + l) * 8];
            acc[nt] = __builtin_amdgcn_mfma_f32_16x16x32_bf16(a, b, acc[nt], 0, 0, 0);
        }
    }
    float v[4][4];
    int cols[4];
#pragma unroll
    for (int nt = 0; nt < 4; ++nt) {
        int col = wv * 64 + nt * 16 + l;
        cols[nt] = col;
        float bb = bcomb[col];
        float4 rx = *(const float4*)&x_nchw[((size_t)(cam * 256 + col)) * HWSZ + hw0q];
        v[nt][0] = acc[nt][0] + bb + rx.x;
        v[nt][1] = acc[nt][1] + bb + rx.y;
        v[nt][2] = acc[nt][2] + bb + rx.z;
        v[nt][3] = acc[nt][3] + bb + rx.w;
    }
    // ---- LN0 ----
#pragma unroll
    for (int r = 0; r < 4; ++r) {
        float s = v[0][r] + v[1][r] + v[2][r] + v[3][r];
        float sq = v[0][r] * v[0][r] + v[1][r] * v[1][r] +
                   v[2][r] * v[2][r] + v[3][r] * v[3][r];
#pragma unroll
        for (int msk = 1; msk <= 8; msk <<= 1) {
            s += __shfl_xor(s, msk);
            sq += __shfl_xor(sq, msk);
        }
        if (l == 0) { red[wv][quad][r][0] = s; red[wv][quad][r][1] = sq; }
    }
    __syncthreads();
    float o0[4][4];
#pragma unroll
    for (int r = 0; r < 4; ++r) {
        float S = red[0][quad][r][0] + red[1][quad][r][0] +
                  red[2][quad][r][0] + red[3][quad][r][0];
        float Q = red[0][quad][r][1] + red[1][quad][r][1] +
                  red[2][quad][r][1] + red[3][quad][r][1];
        float mean = S * (1.0f / 256.0f);
        float var = Q * (1.0f / 256.0f) - mean * mean;
        float rstd = rsqrtf(var + 1e-5f);
        int row = quad * 4 + r;
#pragma unroll
        for (int nt = 0; nt < 4; ++nt) {
            int col = cols[nt];
            float ov = (v[nt][r] - mean) * rstd * n0g[col] + n0b[col];
            o0[nt][r] = ov;
            A2[((col >> 3) * 17 + row) * 8 + (col & 7)] = f2b(ov);
        }
    }
    // ---- GEMM2: lin1 (A from A2) ----
    f32x4 acc2[4] = {};
    for (int k0 = 0; k0 < 256; k0 += 32) {
        __syncthreads();
#pragma unroll
        for (int j = 0; j < 4; ++j)
            *(uint4*)&Bs[(j * 257 + t) * 8] =
                *(const uint4*)&W1[(size_t)t * 256 + k0 + j * 8];
        __syncthreads();
        bf16x8 a = *(const bf16x8*)&A2[(((k0 >> 3) + quad) * 17 + l) * 8];
#pragma unroll
        for (int nt = 0; nt < 4; ++nt) {
            bf16x8 b = *(const bf16x8*)&Bs[(quad * 257 + wv * 64 + nt * 16 + l) * 8];
            acc2[nt] = __builtin_amdgcn_mfma_f32_16x16x32_bf16(a, b, acc2[nt], 0, 0, 0);
        }
    }
    __syncthreads();  // A2 reads done; safe to overwrite
#pragma unroll
    for (int nt = 0; nt < 4; ++nt) {
        int col = cols[nt];
        float bb = b1v[col];
#pragma unroll
        for (int r = 0; r < 4; ++r) {
            int row = quad * 4 + r;
            A2[((col >> 3) * 17 + row) * 8 + (col & 7)] = f2b(fmaxf(acc2[nt][r] + bb, 0.f));
        }
    }
    // ---- GEMM3: lin2 (A from A2) ----
    f32x4 acc3[4] = {};
    for (int k0 = 0; k0 < 256; k0 += 32) {
        __syncthreads();
#pragma unroll
        for (int j = 0; j < 4; ++j)
            *(uint4*)&Bs[(j * 257 + t) * 8] =
                *(const uint4*)&W2[(size_t)t * 256 + k0 + j * 8];
        __syncthreads();
        bf16x8 a = *(const bf16x8*)&A2[(((k0 >> 3) + quad) * 17 + l) * 8];
#pragma unroll
        for (int nt = 0; nt < 4; ++nt) {
            bf16x8 b = *(const bf16x8*)&Bs[(quad * 257 + wv * 64 + nt * 16 + l) * 8];
            acc3[nt] = __builtin_amdgcn_mfma_f32_16x16x32_bf16(a, b, acc3[nt], 0, 0, 0);
        }
    }
    float v2[4][4];
#pragma unroll
    for (int nt = 0; nt < 4; ++nt) {
        float bb = b2v[cols[nt]];
#pragma unroll
        for (int r = 0; r < 4; ++r) v2[nt][r] = acc3[nt][r] + bb + o0[nt][r];
    }
    // ---- LN2 ----
    __syncthreads();
#pragma unroll
    for (int r = 0; r < 4; ++r) {
        float s = v2[0][r] + v2[1][r] + v2[2][r] + v2[3][r];
        float sq = v2[0][r] * v2[0][r] + v2[1][r] * v2[1][r] +
                   v2[2][r] * v2[2][r] + v2[3][r] * v2[3][r];
#pragma unroll
        for (int msk = 1; msk <= 8; msk <<= 1) {
            s += __shfl_xor(s, msk);
            sq += __shfl_xor(sq, msk);
        }
        if (l == 0) { red[wv][quad][r][0] = s; red[wv][quad][r][1] = sq; }
    }
    __syncthreads();
    float mean2[4], rstd2[4];
#pragma unroll
    for (int r = 0; r < 4; ++r) {
        float S = red[0][quad][r][0] + red[1][quad][r][0] +
                  red[2][quad][r][0] + red[3][quad][r][0];
        float Q = red[0][quad][r][1] + red[1][quad][r][1] +
                  red[2][quad][r][1] + red[3][quad][r][1];
        mean2[r] = S * (1.0f / 256.0f);
        float var = Q * (1.0f / 256.0f) - mean2[r] * mean2[r];
        rstd2[r] = rsqrtf(var + 1e-5f);
    }
#pragma unroll
    for (int nt = 0; nt < 4; ++nt) {
        int col = cols[nt];
        float gg = n2g[col], bb = n2b[col];
        float4 ov4;
        ov4.x = (v2[nt][0] - mean2[0]) * rstd2[0] * gg + bb;
        ov4.y = (v2[nt][1] - mean2[1]) * rstd2[1] * gg + bb;
        ov4.z = (v2[nt][2] - mean2[2]) * rstd2[2] * gg + bb;
        ov4.w = (v2[nt][3] - mean2[3]) * rstd2[3] * gg + bb;
        *(float4*)&out_nchw[((size_t)(cam * 256 + col)) * HWSZ + hw0q] = ov4;
    }
}

// ---------------------------------------------------------------------------
extern "C" void kernel_launch(void* const* d_in, const int* in_sizes, int n_in,
                              void* d_out, int out_size, void* d_ws, size_t ws_size,
                              hipStream_t stream) {
    const float* x       = (const float*)d_in[0];
    const float* conv0_w = (const float*)d_in[1];
    const float* conv0_b = (const float*)d_in[2];
    const float* conv2_w = (const float*)d_in[3];
    const float* conv2_b = (const float*)d_in[4];
    const float* cam_emb = (const float*)d_in[5];
    const float* off_w   = (const float*)d_in[6];
    const float* off_b   = (const float*)d_in[7];
    const float* val_w   = (const float*)d_in[8];
    const float* val_b   = (const float*)d_in[9];
    const float* key_w   = (const float*)d_in[10];
    const float* key_b   = (const float*)d_in[11];
    const float* out_w   = (const float*)d_in[12];
    const float* out_b   = (const float*)d_in[13];
    const float* conv1_w = (const float*)d_in[14];
    const float* conv1_b = (const float*)d_in[15];
    const float* norm0_g = (const float*)d_in[16];
    const float* norm0_b = (const float*)d_in[17];
    const float* lin1_w  = (const float*)d_in[18];
    const float* lin1_b  = (const float*)d_in[19];
    const float* lin2_w  = (const float*)d_in[20];
    const float* lin2_b  = (const float*)d_in[21];
    const float* norm2_g = (const float*)d_in[22];
    const float* norm2_b = (const float*)d_in[23];

    float* ws = (float*)d_ws;
    float* pos      = ws;                       // 204800
    float* mu_x     = pos + 204800;             // 1536
    float* g        = mu_x + 1536;              // 1536
    float* camoff   = g + 1536;                 // 2304
    float* posy     = camoff + 2304;            // 7680
    float* posx     = posy + 7680;              // 15360
    float* bias_cat = posx + 15360;             // 1152
    float* bcomb    = bias_cat + 1152;          // 256
    float* offs     = bcomb + 256;              // 1843200
    float* f_xtb    = offs + 1843200;           // 614400 (alias: attn_ob)
    float* f_spcb   = f_xtb + 614400;           // 614400
    float* f_kvcat  = f_spcb + 614400;          // 1228800
    float* f_Wcat   = f_kvcat + 1228800;        // 147456
    float* f_lin1b  = f_Wcat + 147456;          // 32768
    float* f_lin2b  = f_lin1b + 32768;          // 32768
    float* f_wcombb = f_lin2b + 32768;          // 32768

    u16* xtb     = (u16*)f_xtb;
    u16* spcb    = (u16*)f_spcb;
    u16* kvcat16 = (u16*)f_kvcat;
    u16* Wcat    = (u16*)f_Wcat;
    u16* lin1b   = (u16*)f_lin1b;
    u16* lin2b   = (u16*)f_lin2b;
    u16* wcombb  = (u16*)f_wcombb;
    u16* attn_ob = xtb;   // xtb dead after gemm_fused

    prep1<<<P1_BLOCKS, 256, 0, stream>>>(
        x, conv0_w, conv0_b, key_w, key_b, val_w, val_b, off_w, off_b,
        lin1_w, lin2_w, conv1_w, conv1_b, out_w, out_b, cam_emb,
        pos, xtb, mu_x, Wcat, bias_cat, lin1b, lin2b, wcombb, bcomb,
        camoff, posy, posx);
    gemm_fused<<<1356, 256, 0, stream>>>(xtb, Wcat, bias_cat, pos, cam_emb,
                                         spcb, kvcat16, offs, mu_x, conv0_w,
                                         conv0_b, conv2_w, conv2_b, g);
    attn_kernel<<<LQ / 2, 256, 0, stream>>>(spcb, kvcat16, offs, posy, posx,
                                            camoff, g, attn_ob);
    epilogue<<<300, 256, 0, stream>>>(attn_ob, wcombb, bcomb, x,
                                      norm0_g, norm0_b, lin1b, lin1_b,
                                      lin2b, lin2_b, norm2_g, norm2_b,
                                      (float*)d_out);
}

// Round 7
// 215.384 us; speedup vs baseline: 1.2556x; 1.0229x over previous
//
#include <hip/hip_runtime.h>
#include <math.h>

typedef unsigned short u16;
typedef unsigned int u32;

#define NCAM 6
#define NHEADS 8
#define NPOINTS 4
#define DD 256
#define HH 20
#define WW 40
#define HWSZ 800
#define LQ 4800
#define HDIM 32

typedef __attribute__((ext_vector_type(8))) short bf16x8;
typedef __attribute__((ext_vector_type(4))) float f32x4;

__device__ __forceinline__ u16 f2b(float x) {
    union { float f; u32 u; } v;
    v.f = x;
    u32 r = (v.u + 0x7FFFu + ((v.u >> 16) & 1u)) >> 16;  // RNE
    return (u16)r;
}
__device__ __forceinline__ float lo2f(u32 u) {
    union { u32 u; float f; } v; v.u = u << 16; return v.f;
}
__device__ __forceinline__ float hi2f(u32 u) {
    union { u32 u; float f; } v; v.u = u & 0xFFFF0000u; return v.f;
}
__device__ __forceinline__ float red16(float s) {
    s += __shfl_xor(s, 1);
    s += __shfl_xor(s, 2);
    s += __shfl_xor(s, 4);
    s += __shfl_xor(s, 8);
    return s;
}

// ---------------------------------------------------------------------------
// prep1: elementwise-only prep (no serial dots). Block ranges:
// [0,800)       pos fp32
// [800,1184)    xmean (4 rows/block, wave-parallel)
// [1184,3104)   linear bf16 conversions (conv0->Wcat[0:256]+bias, conv1b,
//               lin1b, lin2b, off_wb, kvpackb)
// [3104,3232)   transposing conversions: conv0_wT_b, out_wT_b
// [3232,4432)   transpose x -> xtb (bf16)
// [4432,4492)   posy/posx (16-lane/output reduction)
// [4492,4498)   camoff (16-lane/output reduction)
// [4498,4554)   bias fold rows 256..1151 (16-lane/row)
// [4554,4570)   bcomb (16-lane/row)
#define P1_BLOCKS 4570
__global__ __launch_bounds__(256) void prep1(
    const float* __restrict__ x, const float* __restrict__ conv0_w,
    const float* __restrict__ conv0_b, const float* __restrict__ key_w,
    const float* __restrict__ key_b, const float* __restrict__ val_w,
    const float* __restrict__ val_b, const float* __restrict__ off_w,
    const float* __restrict__ off_b, const float* __restrict__ lin1_w,
    const float* __restrict__ lin2_w, const float* __restrict__ conv1_w,
    const float* __restrict__ conv1_b, const float* __restrict__ out_w,
    const float* __restrict__ out_b, const float* __restrict__ cam_emb,
    float* __restrict__ pos, u16* __restrict__ xtb, float* __restrict__ mu_x,
    u16* __restrict__ Wcat, float* __restrict__ bias_cat,
    u16* __restrict__ conv1b, u16* __restrict__ lin1b, u16* __restrict__ lin2b,
    u16* __restrict__ off_wb, u16* __restrict__ kvpackb,
    u16* __restrict__ conv0_wTb, u16* __restrict__ out_wTb,
    float* __restrict__ bcomb, float* __restrict__ camoff,
    float* __restrict__ posy, float* __restrict__ posx) {
    __shared__ float sbuf[1088];
    int b = blockIdx.x, t = threadIdx.x;
    if (b < 800) {
        int hw = b, d = t;
        int h = hw / WW, w = hw % WW;
        int j = (d & 127) >> 1;
        float dim = powf(10000.0f, (float)j * (1.0f / 64.0f));
        float v;
        if (d < 128) v = (float)(h + 1) / (20.0f + 1e-6f) * (2.0f * (float)M_PI);
        else         v = (float)(w + 1) / (40.0f + 1e-6f) * (2.0f * (float)M_PI);
        float p = v / dim;
        pos[hw * DD + d] = (d & 1) ? cosf(p) : sinf(p);
    } else if (b < 1184) {
        int row = (b - 800) * 4 + (t >> 6);
        int lane = t & 63;
        const float* base = x + (size_t)row * HWSZ;
        float s = 0.f;
        for (int i = lane; i < HWSZ; i += 64) s += base[i];
#pragma unroll
        for (int m = 1; m <= 32; m <<= 1) s += __shfl_xor(s, m);
        if (lane == 0) mu_x[row] = s * (1.0f / (float)HWSZ);
    } else if (b < 3104) {
        int i = (b - 1184) * 256 + t;  // < 491520
        if (i < 65536) {
            Wcat[i] = f2b(conv0_w[i]);
            if (i < 256) bias_cat[i] = conv0_b[i];
        } else if (i < 131072) {
            conv1b[i - 65536] = f2b(conv1_w[i - 65536]);
        } else if (i < 196608) {
            lin1b[i - 131072] = f2b(lin1_w[i - 131072]);
        } else if (i < 262144) {
            lin2b[i - 196608] = f2b(lin2_w[i - 196608]);
        } else if (i < 360448) {
            off_wb[i - 262144] = f2b(off_w[i - 262144]);
        } else {
            int j = i - 360448;  // 0..131071
            int rj = j >> 8, k = j & 255;
            int head = rj >> 6, cpair = (rj >> 1) & 31, kv = rj & 1;
            kvpackb[j] = f2b((kv ? val_w : key_w)[(size_t)(head * 32 + cpair) * 256 + k]);
        }
    } else if (b < 3232) {
        // transposed bf16: dstT[c][k] = f2b(src[k][c])
        int idx = b - 3104;
        int which = idx >> 6;          // 0: conv0_w, 1: out_w
        int t2 = idx & 63;
        int k0 = (t2 >> 3) * 32, c0 = (t2 & 7) * 32;
        const float* src = which ? out_w : conv0_w;
        u16* dst = which ? out_wTb : conv0_wTb;
        float (*tile)[33] = (float(*)[33])sbuf;
        int lc = t & 31, lk4 = t >> 5;
#pragma unroll
        for (int i = 0; i < 4; ++i) {
            int lk = lk4 * 4 + i;
            tile[lk][lc] = src[(size_t)(k0 + lk) * 256 + c0 + lc];
        }
        __syncthreads();
        int lk2 = t & 31, lc4 = t >> 5;
#pragma unroll
        for (int i = 0; i < 4; ++i) {
            int lc2 = lc4 * 4 + i;
            dst[(size_t)(c0 + lc2) * 256 + k0 + lk2] = f2b(tile[lk2][lc2]);
        }
    } else if (b < 4432) {
        int idx = b - 3232;  // 0..1199
        int cam = idx / 200, rem = idx % 200;
        int hw0 = (rem % 25) * 32, c0 = (rem / 25) * 32;
        float (*tile)[33] = (float(*)[33])sbuf;
        int lhw = t & 31, lc4 = t >> 5;
#pragma unroll
        for (int i = 0; i < 4; ++i) {
            int lc = lc4 * 4 + i;
            tile[lc][lhw] = x[((size_t)(cam * DD + c0 + lc)) * HWSZ + hw0 + lhw];
        }
        __syncthreads();
        int lc2 = t & 31, lhw4 = t >> 5;
#pragma unroll
        for (int i = 0; i < 4; ++i) {
            int lhw2 = lhw4 * 4 + i;
            xtb[((size_t)(cam * HWSZ + hw0 + lhw2)) * DD + c0 + lc2] =
                f2b(tile[lc2][lhw2]);
        }
    } else if (b < 4492) {
        // posy[h][n] / posx[w][n]: 16 lanes x 8 elems per output
        int idx = b - 4432;  // 0..59
        int yside = (idx < 20);
        int coord = yside ? idx : idx - 20;
        if (t < 128) {
            int d = t, j = d >> 1;
            float dim = powf(10000.0f, (float)j * (1.0f / 64.0f));
            float v = yside
                ? (float)(coord + 1) / (20.0f + 1e-6f) * (2.0f * (float)M_PI)
                : (float)(coord + 1) / (40.0f + 1e-6f) * (2.0f * (float)M_PI);
            float p = v / dim;
            sbuf[d] = (d & 1) ? cosf(p) : sinf(p);
        }
        __syncthreads();
        int koff = yside ? 0 : 128;
        float* outp = yside ? (posy + coord * 384) : (posx + coord * 384);
        int l = t & 15, og = t >> 4;
#pragma unroll
        for (int chunk = 0; chunk < 24; ++chunk) {
            int n = chunk * 16 + og;
            const float* wr = off_w + (size_t)n * 256 + koff + l * 8;
            float4 w0 = *(const float4*)wr;
            float4 w1 = *(const float4*)(wr + 4);
            const float* pv = sbuf + l * 8;
            float s = pv[0] * w0.x + pv[1] * w0.y + pv[2] * w0.z + pv[3] * w0.w +
                      pv[4] * w1.x + pv[5] * w1.y + pv[6] * w1.z + pv[7] * w1.w;
            s = red16(s);
            if (l == 0) outp[n] = s;
        }
    } else if (b < 4498) {
        int cam = b - 4492;
        sbuf[t] = cam_emb[cam * DD + t];
        __syncthreads();
        int l = t & 15, og = t >> 4;
#pragma unroll
        for (int chunk = 0; chunk < 24; ++chunk) {
            int n = chunk * 16 + og;
            const float* wr = off_w + (size_t)n * 256 + l * 16;
            float s = 0.f;
#pragma unroll
            for (int i = 0; i < 4; ++i) {
                float4 w4 = *(const float4*)(wr + i * 4);
                const float* ce = sbuf + l * 16 + i * 4;
                s += ce[0] * w4.x + ce[1] * w4.y + ce[2] * w4.z + ce[3] * w4.w;
            }
            s = red16(s);
            if (l == 0) camoff[cam * 384 + n] = s;
        }
    } else if (b < 4554) {
        // bias fold: bias_cat[256+rr] = b_src[rr] + rowsrc[rr] . conv0_b
        sbuf[t] = conv0_b[t];
        __syncthreads();
        int l = t & 15, og = t >> 4;
        int rr = (b - 4498) * 16 + og;  // 0..895
        const float* srcp;
        float bsrc;
        if (rr < 512) {
            int head = rr >> 6, cpair = (rr >> 1) & 31, kv = rr & 1;
            srcp = (kv ? val_w : key_w) + (size_t)(head * 32 + cpair) * 256;
            bsrc = (kv ? val_b : key_b)[head * 32 + cpair];
        } else {
            srcp = off_w + (size_t)(rr - 512) * 256;
            bsrc = off_b[rr - 512];
        }
        float s = 0.f;
#pragma unroll
        for (int i = 0; i < 4; ++i) {
            float4 w4 = *(const float4*)(srcp + l * 16 + i * 4);
            const float* cb = sbuf + l * 16 + i * 4;
            s += cb[0] * w4.x + cb[1] * w4.y + cb[2] * w4.z + cb[3] * w4.w;
        }
        s = red16(s);
        if (l == 0) bias_cat[256 + rr] = bsrc + s;
    } else {
        // bcomb[n] = conv1_b[n] + conv1_w[n] . out_b
        sbuf[t] = out_b[t];
        __syncthreads();
        int l = t & 15, og = t >> 4;
        int n = (b - 4554) * 16 + og;  // 0..255
        float s = 0.f;
#pragma unroll
        for (int i = 0; i < 4; ++i) {
            float4 w4 = *(const float4*)(conv1_w + (size_t)n * 256 + l * 16 + i * 4);
            const float* ob = sbuf + l * 16 + i * 4;
            s += ob[0] * w4.x + ob[1] * w4.y + ob[2] * w4.z + ob[3] * w4.w;
        }
        s = red16(s);
        if (l == 0) bcomb[n] = conv1_b[n] + s;
    }
}

// ---------------------------------------------------------------------------
// prep2: MFMA weight folds (32x128 tiles).
// b<56:  Wcat rows 256..1151 = [kvpack|off] @ conv0_w  (A bf16 @ conv0_wT^T)
// b>=56: wcombb = conv1_w @ out_w                      (conv1b @ out_wT^T)
__global__ __launch_bounds__(256) void prep2(
    const u16* __restrict__ kvpackb, const u16* __restrict__ off_wb,
    const u16* __restrict__ conv0_wTb, const u16* __restrict__ conv1b,
    const u16* __restrict__ out_wTb, u16* __restrict__ Wcat,
    u16* __restrict__ wcombb) {
    __shared__ __align__(16) u16 As[1056];
    __shared__ __align__(16) u16 Bs[4120];
    int b = blockIdx.x, t = threadIdx.x;
    int isfold = (b < 56);
    int bb = isfold ? b : b - 56;
    int row0 = (bb >> 1) * 32, col0 = (bb & 1) * 128;
    const u16* Wb = isfold ? conv0_wTb : out_wTb;
    int wv = t >> 6, lane = t & 63;
    int quad = lane >> 4, l = lane & 15;
    f32x4 acc[2][2] = {};
    for (int k0 = 0; k0 < 256; k0 += 32) {
        __syncthreads();
        if (t < 128) {
            int m = t >> 2, j = t & 3;
            int rr = row0 + m;
            const u16* ap;
            if (isfold) ap = (rr < 512) ? (kvpackb + (size_t)rr * 256)
                                        : (off_wb + (size_t)(rr - 512) * 256);
            else        ap = conv1b + (size_t)rr * 256;
            *(uint4*)&As[(j * 33 + m) * 8] = *(const uint4*)&ap[k0 + j * 8];
        }
        {
            int n = t >> 1, jp = (t & 1) * 2;
            const u16* gsrc = &Wb[(size_t)(col0 + n) * 256 + k0 + jp * 8];
            *(uint4*)&Bs[(jp * 129 + n) * 8]       = *(const uint4*)gsrc;
            *(uint4*)&Bs[((jp + 1) * 129 + n) * 8] = *(const uint4*)(gsrc + 8);
        }
        __syncthreads();
        bf16x8 a0 = *(const bf16x8*)&As[(quad * 33 + l) * 8];
        bf16x8 a1 = *(const bf16x8*)&As[(quad * 33 + 16 + l) * 8];
        bf16x8 b0 = *(const bf16x8*)&Bs[(quad * 129 + wv * 32 + l) * 8];
        bf16x8 b1 = *(const bf16x8*)&Bs[(quad * 129 + wv * 32 + 16 + l) * 8];
        acc[0][0] = __builtin_amdgcn_mfma_f32_16x16x32_bf16(a0, b0, acc[0][0], 0, 0, 0);
        acc[0][1] = __builtin_amdgcn_mfma_f32_16x16x32_bf16(a0, b1, acc[0][1], 0, 0, 0);
        acc[1][0] = __builtin_amdgcn_mfma_f32_16x16x32_bf16(a1, b0, acc[1][0], 0, 0, 0);
        acc[1][1] = __builtin_amdgcn_mfma_f32_16x16x32_bf16(a1, b1, acc[1][1], 0, 0, 0);
    }
#pragma unroll
    for (int mt = 0; mt < 2; ++mt) {
#pragma unroll
        for (int nt = 0; nt < 2; ++nt) {
            int col = col0 + wv * 32 + nt * 16 + l;
#pragma unroll
            for (int r = 0; r < 4; ++r) {
                int rr = row0 + mt * 16 + quad * 4 + r;
                u16 ov = f2b(acc[mt][nt][r]);
                if (isfold) Wcat[(size_t)(256 + rr) * 256 + col] = ov;
                else        wcombb[(size_t)rr * 256 + col] = ov;
            }
        }
    }
}

// ---------------------------------------------------------------------------
// gemm_fused: blocks [0,675) BM=64 x BN=128 GEMM on xtb over Wcat (N=1152):
// cols 0..255 conv0->spcb(+pos+cam), 256..767 kv->bf16, 768..1151 offs fp32.
// blocks [675,681): meang (g per cam).
__global__ __launch_bounds__(256) void gemm_fused(
    const u16* __restrict__ Ab, const u16* __restrict__ Wcat,
    const float* __restrict__ bias_cat, const float* __restrict__ pos,
    const float* __restrict__ cam_emb, u16* __restrict__ spcb,
    u16* __restrict__ kvcat16, float* __restrict__ offs,
    const float* __restrict__ mu_x, const float* __restrict__ conv0_w,
    const float* __restrict__ conv0_b, const float* __restrict__ conv2_w,
    const float* __restrict__ conv2_b, float* __restrict__ g) {
    int b = blockIdx.x, t = threadIdx.x;
    if (b < 675) {
        __shared__ __align__(16) u16 As[2080];   // [j][65 pitch rows][8]
        __shared__ __align__(16) u16 Bs[4120];
        int col0 = (b % 9) * 128, row0 = (b / 9) * 64;
        int wv = t >> 6, lane = t & 63;
        int quad = lane >> 4, l = lane & 15;
        f32x4 acc[4][2] = {};
        for (int k0 = 0; k0 < 256; k0 += 32) {
            __syncthreads();
            {
                int m = t >> 2, j = t & 3;
                *(uint4*)&As[(j * 65 + m) * 8] =
                    *(const uint4*)&Ab[(size_t)(row0 + m) * 256 + k0 + j * 8];
            }
            {
                int n = t >> 1, jp = (t & 1) * 2;
                const u16* gsrc = &Wcat[(size_t)(col0 + n) * 256 + k0 + jp * 8];
                *(uint4*)&Bs[(jp * 129 + n) * 8]       = *(const uint4*)gsrc;
                *(uint4*)&Bs[((jp + 1) * 129 + n) * 8] = *(const uint4*)(gsrc + 8);
            }
            __syncthreads();
            bf16x8 b0 = *(const bf16x8*)&Bs[(quad * 129 + wv * 32 + l) * 8];
            bf16x8 b1 = *(const bf16x8*)&Bs[(quad * 129 + wv * 32 + 16 + l) * 8];
#pragma unroll
            for (int mt = 0; mt < 4; ++mt) {
                bf16x8 a = *(const bf16x8*)&As[(quad * 65 + mt * 16 + l) * 8];
                acc[mt][0] = __builtin_amdgcn_mfma_f32_16x16x32_bf16(a, b0, acc[mt][0], 0, 0, 0);
                acc[mt][1] = __builtin_amdgcn_mfma_f32_16x16x32_bf16(a, b1, acc[mt][1], 0, 0, 0);
            }
        }
#pragma unroll
        for (int mt = 0; mt < 4; ++mt) {
#pragma unroll
            for (int nt = 0; nt < 2; ++nt) {
                int col = col0 + wv * 32 + nt * 16 + l;
                float bb = bias_cat[col];
#pragma unroll
                for (int r = 0; r < 4; ++r) {
                    int row = row0 + mt * 16 + quad * 4 + r;
                    float v = acc[mt][nt][r] + bb;
                    if (col0 < 256) {
                        int cam = row / HWSZ, hw = row % HWSZ;
                        spcb[(size_t)row * 256 + col] =
                            f2b(v + pos[(size_t)hw * 256 + col] + cam_emb[cam * 256 + col]);
                    } else if (col0 < 768) {
                        kvcat16[(size_t)row * 512 + (col - 256)] = f2b(v);
                    } else {
                        offs[(size_t)row * 384 + (col - 768)] = v;
                    }
                }
            }
        }
    } else {
        int cam = b - 675;
        __shared__ float mu[DD];
        __shared__ float smu[DD];
        float pm;
        {
            int d = t;
            int j = (d & 127) >> 1;
            float inv = 1.0f / powf(10000.0f, (float)j * (1.0f / 64.0f));
            float s = 0.f;
            if (d < 128) {
                for (int h = 0; h < HH; ++h) {
                    float p = (float)(h + 1) / (20.0f + 1e-6f) * (2.0f * (float)M_PI) * inv;
                    s += (d & 1) ? cosf(p) : sinf(p);
                }
                pm = s * (1.0f / (float)HH);
            } else {
                for (int w = 0; w < WW; ++w) {
                    float p = (float)(w + 1) / (40.0f + 1e-6f) * (2.0f * (float)M_PI) * inv;
                    s += (d & 1) ? cosf(p) : sinf(p);
                }
                pm = s * (1.0f / (float)WW);
            }
        }
        mu[t] = mu_x[cam * DD + t];
        __syncthreads();
        float a = conv0_b[t] + pm + cam_emb[cam * DD + t];
        const float* wr = conv0_w + (size_t)t * DD;
        for (int k = 0; k < DD; ++k) a += mu[k] * wr[k];
        smu[t] = a;
        __syncthreads();
        float ga = conv2_b[t];
        const float* w2r = conv2_w + (size_t)t * DD;
        for (int d = 0; d < DD; ++d) ga += smu[d] * w2r[d];
        g[cam * DD + t] = ga;
    }
}

// ---------------------------------------------------------------------------
// Deformable attention: 2 queries/block, 16 lanes/head (2 ch/lane), staged
// bilinear (separate 4B arrays), 2-cam logit batching (10-wide softmax update).
__global__ __launch_bounds__(256, 4) void attn_kernel(
    const u16* __restrict__ spcb, const u16* __restrict__ kvcat16,
    const float* __restrict__ offs, const float* __restrict__ posy,
    const float* __restrict__ posx, const float* __restrict__ camoff,
    const float* __restrict__ g, u16* __restrict__ attn_out) {
    int qq = blockIdx.x;
    int q0 = qq * 2;
    int tid = threadIdx.x;
    int cam = q0 / HWSZ;
    int hw0 = q0 % HWSZ;
    __shared__ float soff[2][384];
    __shared__ float wgt[2][192][4];
    __shared__ int   idxp[2][192][4];
    for (int i = tid; i < 768; i += 256) {
        int qi = i / 384, n = i - qi * 384;
        int hw = hw0 + qi;
        int h = hw / WW, w = hw - h * WW;
        soff[qi][n] = offs[(size_t)(q0 + qi) * 384 + n] + posy[h * 384 + n] +
                      posx[w * 384 + n] + camoff[cam * 384 + n];
    }
    __syncthreads();
    for (int e2 = tid; e2 < 384; e2 += 256) {
        int qi = e2 / 192, e = e2 - qi * 192;
        int head = e / 24, r = e - head * 24;
        int scam = r >> 2;
        int hw = hw0 + qi;
        int h = hw / WW, w = hw - h * WW;
        float X = (float)w + soff[qi][e * 2];
        float Y = (float)h + soff[qi][e * 2 + 1];
        float x0f = floorf(X), y0f = floorf(Y);
        float fx = X - x0f, fy = Y - y0f;
        int x0 = (int)x0f, y0 = (int)y0f, x1 = x0 + 1, y1 = y0 + 1;
        float vx0 = (x0 >= 0 && x0 < WW) ? 1.f : 0.f;
        float vx1 = (x1 >= 0 && x1 < WW) ? 1.f : 0.f;
        float vy0 = (y0 >= 0 && y0 < HH) ? 1.f : 0.f;
        float vy1 = (y1 >= 0 && y1 < HH) ? 1.f : 0.f;
        int cx0 = min(max(x0, 0), WW - 1), cx1 = min(max(x1, 0), WW - 1);
        int cy0 = min(max(y0, 0), HH - 1), cy1 = min(max(y1, 0), HH - 1);
        wgt[qi][e][0] = (1.f - fx) * (1.f - fy) * vx0 * vy0;
        wgt[qi][e][1] = fx * (1.f - fy) * vx1 * vy0;
        wgt[qi][e][2] = (1.f - fx) * fy * vx0 * vy1;
        wgt[qi][e][3] = fx * fy * vx1 * vy1;
        int pb = scam * HWSZ, hb = head * 64;
        idxp[qi][e][0] = ((pb + cy0 * WW + cx0) << 9) + hb;
        idxp[qi][e][1] = ((pb + cy0 * WW + cx1) << 9) + hb;
        idxp[qi][e][2] = ((pb + cy1 * WW + cx0) << 9) + hb;
        idxp[qi][e][3] = ((pb + cy1 * WW + cx1) << 9) + hb;
    }
    __syncthreads();
    int qi = tid >> 7, head = (tid >> 4) & 7, l = tid & 15;
    int q = q0 + qi;
    int c0 = l * 2;
    u32 qu = *(const u32*)&spcb[(size_t)q * 256 + head * 32 + c0];
    const float scale = 0.17677669529663687f;  // 1/sqrt(32)
    float q0s = lo2f(qu) * scale, q1s = hi2f(qu) * scale;
    float m = -1e30f, den = 0.f, o0 = 0.f, o1 = 0.f;
    int l4 = 4 * l;
    for (int scp = 0; scp < 3; ++scp) {
        int e0i = head * 24 + scp * 8;
        float av0[8], av1[8], lg[8];
#pragma unroll
        for (int p = 0; p < 8; ++p) {
            int e = e0i + p;
            float ak0 = 0.f, ak1 = 0.f, a0 = 0.f, a1 = 0.f;
#pragma unroll
            for (int j = 0; j < 4; ++j) {
                float wj = wgt[qi][e][j];
                int idx = idxp[qi][e][j] + l4;
                uint2 d = *(const uint2*)&kvcat16[idx];  // k0,v0,k1,v1
                ak0 += wj * lo2f(d.x);
                a0  += wj * hi2f(d.x);
                ak1 += wj * lo2f(d.y);
                a1  += wj * hi2f(d.y);
            }
            av0[p] = a0; av1[p] = a1;
            float pl = q0s * ak0 + q1s * ak1;
            lg[p] = red16(pl);
        }
        float2 gva = *(const float2*)&g[(scp * 2) * 256 + head * 32 + c0];
        float2 gvb = *(const float2*)&g[(scp * 2 + 1) * 256 + head * 32 + c0];
        float pga = red16(q0s * gva.x + q1s * gva.y);
        float pgb = red16(q0s * gvb.x + q1s * gvb.y);
        // batched online-softmax update: 10 logits
        float mc = fmaxf(pga, pgb);
#pragma unroll
        for (int p = 0; p < 8; ++p) mc = fmaxf(mc, lg[p]);
        float mn = fmaxf(m, mc);
        float aa = __expf(m - mn);
        float ee[8];
        float dsum = 0.f, s0 = 0.f, s1 = 0.f;
#pragma unroll
        for (int p = 0; p < 8; ++p) {
            ee[p] = __expf(lg[p] - mn);
            dsum += ee[p];
            s0 += ee[p] * av0[p];
            s1 += ee[p] * av1[p];
        }
        float ea = __expf(pga - mn), eb = __expf(pgb - mn);
        dsum += ea + eb;
        s0 += ea * gva.x + eb * gvb.x;
        s1 += ea * gva.y + eb * gvb.y;
        den = den * aa + dsum;
        o0 = o0 * aa + s0;
        o1 = o1 * aa + s1;
        m = mn;
    }
    float inv = 1.f / den;
    u32 pack = (u32)f2b(o0 * inv) | ((u32)f2b(o1 * inv) << 16);
    *(u32*)&attn_out[(size_t)q * 256 + head * 32 + c0] = pack;
}

// ---------------------------------------------------------------------------
// Mega-epilogue (grid 300, 16 rows/block): comb+res+LN0 -> lin1+relu ->
// lin2+res+LN2 -> d_out (NCHW float4). Intermediates in LDS/regs.
__global__ __launch_bounds__(256) void epilogue(
    const u16* __restrict__ Ab, const u16* __restrict__ Wc,
    const float* __restrict__ bcomb, const float* __restrict__ x_nchw,
    const float* __restrict__ n0g, const float* __restrict__ n0b,
    const u16* __restrict__ W1, const float* __restrict__ b1v,
    const u16* __restrict__ W2, const float* __restrict__ b2v,
    const float* __restrict__ n2g, const float* __restrict__ n2b,
    float* __restrict__ out_nchw) {
    __shared__ __align__(16) u16 As[552];
    __shared__ __align__(16) u16 Bs[8232];
    __shared__ __align__(16) u16 A2[4360];
    __shared__ float red[4][4][4][2];
    int t = threadIdx.x;
    int row0 = blockIdx.x * 16;
    int wv = t >> 6, lane = t & 63, quad = lane >> 4, l = lane & 15;
    int cam = row0 / HWSZ;
    int hw0q = row0 % HWSZ + quad * 4;

    f32x4 acc[4] = {};
    for (int k0 = 0; k0 < 256; k0 += 32) {
        __syncthreads();
        if (t < 64) {
            int mm = t >> 2, j = t & 3;
            *(uint4*)&As[(j * 17 + mm) * 8] =
                *(const uint4*)&Ab[(size_t)(row0 + mm) * 256 + k0 + j * 8];
        }
#pragma unroll
        for (int j = 0; j < 4; ++j)
            *(uint4*)&Bs[(j * 257 + t) * 8] =
                *(const uint4*)&Wc[(size_t)t * 256 + k0 + j * 8];
        __syncthreads();
        bf16x8 a = *(const bf16x8*)&As[(quad * 17 + l) * 8];
#pragma unroll
        for (int nt = 0; nt < 4; ++nt) {
            bf16x8 b = *(const bf16x8*)&Bs[(quad * 257 + wv * 64 + nt * 16 + l) * 8];
            acc[nt] = __builtin_amdgcn_mfma_f32_16x16x32_bf16(a, b, acc[nt], 0, 0, 0);
        }
    }
    float v[4][4];
    int cols[4];
#pragma unroll
    for (int nt = 0; nt < 4; ++nt) {
        int col = wv * 64 + nt * 16 + l;
        cols[nt] = col;
        float bb = bcomb[col];
        float4 rx = *(const float4*)&x_nchw[((size_t)(cam * 256 + col)) * HWSZ + hw0q];
        v[nt][0] = acc[nt][0] + bb + rx.x;
        v[nt][1] = acc[nt][1] + bb + rx.y;
        v[nt][2] = acc[nt][2] + bb + rx.z;
        v[nt][3] = acc[nt][3] + bb + rx.w;
    }
#pragma unroll
    for (int r = 0; r < 4; ++r) {
        float s = v[0][r] + v[1][r] + v[2][r] + v[3][r];
        float sq = v[0][r] * v[0][r] + v[1][r] * v[1][r] +
                   v[2][r] * v[2][r] + v[3][r] * v[3][r];
#pragma unroll
        for (int msk = 1; msk <= 8; msk <<= 1) {
            s += __shfl_xor(s, msk);
            sq += __shfl_xor(sq, msk);
        }
        if (l == 0) { red[wv][quad][r][0] = s; red[wv][quad][r][1] = sq; }
    }
    __syncthreads();
    float o0[4][4];
#pragma unroll
    for (int r = 0; r < 4; ++r) {
        float S = red[0][quad][r][0] + red[1][quad][r][0] +
                  red[2][quad][r][0] + red[3][quad][r][0];
        float Q = red[0][quad][r][1] + red[1][quad][r][1] +
                  red[2][quad][r][1] + red[3][quad][r][1];
        float mean = S * (1.0f / 256.0f);
        float var = Q * (1.0f / 256.0f) - mean * mean;
        float rstd = rsqrtf(var + 1e-5f);
        int row = quad * 4 + r;
#pragma unroll
        for (int nt = 0; nt < 4; ++nt) {
            int col = cols[nt];
            float ov = (v[nt][r] - mean) * rstd * n0g[col] + n0b[col];
            o0[nt][r] = ov;
            A2[((col >> 3) * 17 + row) * 8 + (col & 7)] = f2b(ov);
        }
    }
    f32x4 acc2[4] = {};
    for (int k0 = 0; k0 < 256; k0 += 32) {
        __syncthreads();
#pragma unroll
        for (int j = 0; j < 4; ++j)
            *(uint4*)&Bs[(j * 257 + t) * 8] =
                *(const uint4*)&W1[(size_t)t * 256 + k0 + j * 8];
        __syncthreads();
        bf16x8 a = *(const bf16x8*)&A2[(((k0 >> 3) + quad) * 17 + l) * 8];
#pragma unroll
        for (int nt = 0; nt < 4; ++nt) {
            bf16x8 b = *(const bf16x8*)&Bs[(quad * 257 + wv * 64 + nt * 16 + l) * 8];
            acc2[nt] = __builtin_amdgcn_mfma_f32_16x16x32_bf16(a, b, acc2[nt], 0, 0, 0);
        }
    }
    __syncthreads();
#pragma unroll
    for (int nt = 0; nt < 4; ++nt) {
        int col = cols[nt];
        float bb = b1v[col];
#pragma unroll
        for (int r = 0; r < 4; ++r) {
            int row = quad * 4 + r;
            A2[((col >> 3) * 17 + row) * 8 + (col & 7)] = f2b(fmaxf(acc2[nt][r] + bb, 0.f));
        }
    }
    f32x4 acc3[4] = {};
    for (int k0 = 0; k0 < 256; k0 += 32) {
        __syncthreads();
#pragma unroll
        for (int j = 0; j < 4; ++j)
            *(uint4*)&Bs[(j * 257 + t) * 8] =
                *(const uint4*)&W2[(size_t)t * 256 + k0 + j * 8];
        __syncthreads();
        bf16x8 a = *(const bf16x8*)&A2[(((k0 >> 3) + quad) * 17 + l) * 8];
#pragma unroll
        for (int nt = 0; nt < 4; ++nt) {
            bf16x8 b = *(const bf16x8*)&Bs[(quad * 257 + wv * 64 + nt * 16 + l) * 8];
            acc3[nt] = __builtin_amdgcn_mfma_f32_16x16x32_bf16(a, b, acc3[nt], 0, 0, 0);
        }
    }
    float v2[4][4];
#pragma unroll
    for (int nt = 0; nt < 4; ++nt) {
        float bb = b2v[cols[nt]];
#pragma unroll
        for (int r = 0; r < 4; ++r) v2[nt][r] = acc3[nt][r] + bb + o0[nt][r];
    }
    __syncthreads();
#pragma unroll
    for (int r = 0; r < 4; ++r) {
        float s = v2[0][r] + v2[1][r] + v2[2][r] + v2[3][r];
        float sq = v2[0][r] * v2[0][r] + v2[1][r] * v2[1][r] +
                   v2[2][r] * v2[2][r] + v2[3][r] * v2[3][r];
#pragma unroll
        for (int msk = 1; msk <= 8; msk <<= 1) {
            s += __shfl_xor(s, msk);
            sq += __shfl_xor(sq, msk);
        }
        if (l == 0) { red[wv][quad][r][0] = s; red[wv][quad][r][1] = sq; }
    }
    __syncthreads();
    float mean2[4], rstd2[4];
#pragma unroll
    for (int r = 0; r < 4; ++r) {
        float S = red[0][quad][r][0] + red[1][quad][r][0] +
                  red[2][quad][r][0] + red[3][quad][r][0];
        float Q = red[0][quad][r][1] + red[1][quad][r][1] +
                  red[2][quad][r][1] + red[3][quad][r][1];
        mean2[r] = S * (1.0f / 256.0f);
        float var = Q * (1.0f / 256.0f) - mean2[r] * mean2[r];
        rstd2[r] = rsqrtf(var + 1e-5f);
    }
#pragma unroll
    for (int nt = 0; nt < 4; ++nt) {
        int col = cols[nt];
        float gg = n2g[col], bb = n2b[col];
        float4 ov4;
        ov4.x = (v2[nt][0] - mean2[0]) * rstd2[0] * gg + bb;
        ov4.y = (v2[nt][1] - mean2[1]) * rstd2[1] * gg + bb;
        ov4.z = (v2[nt][2] - mean2[2]) * rstd2[2] * gg + bb;
        ov4.w = (v2[nt][3] - mean2[3]) * rstd2[3] * gg + bb;
        *(float4*)&out_nchw[((size_t)(cam * 256 + col)) * HWSZ + hw0q] = ov4;
    }
}

// ---------------------------------------------------------------------------
extern "C" void kernel_launch(void* const* d_in, const int* in_sizes, int n_in,
                              void* d_out, int out_size, void* d_ws, size_t ws_size,
                              hipStream_t stream) {
    const float* x       = (const float*)d_in[0];
    const float* conv0_w = (const float*)d_in[1];
    const float* conv0_b = (const float*)d_in[2];
    const float* conv2_w = (const float*)d_in[3];
    const float* conv2_b = (const float*)d_in[4];
    const float* cam_emb = (const float*)d_in[5];
    const float* off_w   = (const float*)d_in[6];
    const float* off_b   = (const float*)d_in[7];
    const float* val_w   = (const float*)d_in[8];
    const float* val_b   = (const float*)d_in[9];
    const float* key_w   = (const float*)d_in[10];
    const float* key_b   = (const float*)d_in[11];
    const float* out_w   = (const float*)d_in[12];
    const float* out_b   = (const float*)d_in[13];
    const float* conv1_w = (const float*)d_in[14];
    const float* conv1_b = (const float*)d_in[15];
    const float* norm0_g = (const float*)d_in[16];
    const float* norm0_b = (const float*)d_in[17];
    const float* lin1_w  = (const float*)d_in[18];
    const float* lin1_b  = (const float*)d_in[19];
    const float* lin2_w  = (const float*)d_in[20];
    const float* lin2_b  = (const float*)d_in[21];
    const float* norm2_g = (const float*)d_in[22];
    const float* norm2_b = (const float*)d_in[23];

    float* ws = (float*)d_ws;
    const size_t SZ = (size_t)LQ * DD;
    float* pos      = ws;                       // 204800
    float* mu_x     = pos + 204800;             // 1536
    float* g        = mu_x + 1536;              // 1536
    float* camoff   = g + 1536;                 // 2304
    float* posy     = camoff + 2304;            // 7680
    float* posx     = posy + 7680;              // 15360
    float* bias_cat = posx + 15360;             // 1152
    float* bcomb    = bias_cat + 1152;          // 256
    float* offs     = bcomb + 256;              // 1843200
    float* f_xtb    = offs + 1843200;           // 614400 (alias: attn_ob)
    float* f_spcb   = f_xtb + 614400;           // 614400
    float* f_kvcat  = f_spcb + 614400;          // 1228800
    float* f_Wcat   = f_kvcat + 1228800;        // 147456
    float* f_lin1b  = f_Wcat + 147456;          // 32768
    float* f_lin2b  = f_lin1b + 32768;          // 32768
    float* f_wcombb = f_lin2b + 32768;          // 32768
    float* f_conv1b = f_wcombb + 32768;         // 32768
    float* f_off_wb = f_conv1b + 32768;         // 49152
    float* f_kvpack = f_off_wb + 49152;         // 65536
    float* f_c0T    = f_kvpack + 65536;         // 32768
    float* f_outT   = f_c0T + 32768;            // 32768

    u16* xtb      = (u16*)f_xtb;
    u16* spcb     = (u16*)f_spcb;
    u16* kvcat16  = (u16*)f_kvcat;
    u16* Wcat     = (u16*)f_Wcat;
    u16* lin1b    = (u16*)f_lin1b;
    u16* lin2b    = (u16*)f_lin2b;
    u16* wcombb   = (u16*)f_wcombb;
    u16* conv1b   = (u16*)f_conv1b;
    u16* off_wb   = (u16*)f_off_wb;
    u16* kvpackb  = (u16*)f_kvpack;
    u16* conv0_wTb= (u16*)f_c0T;
    u16* out_wTb  = (u16*)f_outT;
    u16* attn_ob  = xtb;   // xtb dead after gemm_fused

    prep1<<<P1_BLOCKS, 256, 0, stream>>>(
        x, conv0_w, conv0_b, key_w, key_b, val_w, val_b, off_w, off_b,
        lin1_w, lin2_w, conv1_w, conv1_b, out_w, out_b, cam_emb,
        pos, xtb, mu_x, Wcat, bias_cat, conv1b, lin1b, lin2b,
        off_wb, kvpackb, conv0_wTb, out_wTb, bcomb, camoff, posy, posx);
    prep2<<<72, 256, 0, stream>>>(kvpackb, off_wb, conv0_wTb, conv1b, out_wTb,
                                  Wcat, wcombb);
    gemm_fused<<<681, 256, 0, stream>>>(xtb, Wcat, bias_cat, pos, cam_emb,
                                        spcb, kvcat16, offs, mu_x, conv0_w,
                                        conv0_b, conv2_w, conv2_b, g);
    attn_kernel<<<LQ / 2, 256, 0, stream>>>(spcb, kvcat16, offs, posy, posx,
                                            camoff, g, attn_ob);
    epilogue<<<300, 256, 0, stream>>>(attn_ob, wcombb, bcomb, x,
                                      norm0_g, norm0_b, lin1b, lin1_b,
                                      lin2b, lin2_b, norm2_g, norm2_b,
                                      (float*)d_out);
}

// Round 9
// 200.771 us; speedup vs baseline: 1.3470x; 1.0728x over previous
//
#include <hip/hip_runtime.h>
#include <math.h>

typedef unsigned short u16;
typedef unsigned int u32;

#define NCAM 6
#define NHEADS 8
#define NPOINTS 4
#define DD 256
#define HH 20
#define WW 40
#define HWSZ 800
#define LQ 4800
#define HDIM 32

typedef __attribute__((ext_vector_type(8))) short bf16x8;
typedef __attribute__((ext_vector_type(4))) float f32x4;

__device__ __forceinline__ u16 f2b(float x) {
    union { float f; u32 u; } v;
    v.f = x;
    u32 r = (v.u + 0x7FFFu + ((v.u >> 16) & 1u)) >> 16;  // RNE
    return (u16)r;
}
__device__ __forceinline__ float lo2f(u32 u) {
    union { u32 u; float f; } v; v.u = u << 16; return v.f;
}
__device__ __forceinline__ float hi2f(u32 u) {
    union { u32 u; float f; } v; v.u = u & 0xFFFF0000u; return v.f;
}
__device__ __forceinline__ float red16(float s) {
    s += __shfl_xor(s, 1);
    s += __shfl_xor(s, 2);
    s += __shfl_xor(s, 4);
    s += __shfl_xor(s, 8);
    return s;
}
// async global->LDS, 16B per lane, dest = base + lane*16 (wave-uniform base)
__device__ __forceinline__ void gl_lds16(const void* g, void* l) {
    __builtin_amdgcn_global_load_lds(
        (const __attribute__((address_space(1))) void*)g,
        (__attribute__((address_space(3))) void*)l, 16, 0, 0);
}

// k-major layouts: elem(row,k) at ((k>>3)*NR + row)*8 + (k&7)
// xtb_t: NR=4800 (row=cam*800+hw, k=channel)   Wcat_t: NR=1152 (row=n)
// wcombb_t/lin1b_t/lin2b_t: NR=256

// ---------------------------------------------------------------------------
// prep: one-shot heterogeneous prep. Block ranges:
// [0,800)       pos fp32
// [800,1184)    xmean
// [1184,1952)   bf16 conversions -> Wcat_t[n<256] (+bias), lin1b_t, lin2b_t
// [1952,3152)   transpose x -> xtb_t (bf16 k-major)
// [3152,3212)   posy/posx tables
// [3212,3218)   camoff
// [3218,3274)   bias fold rows 256..1151
// [3274,3290)   bcomb
// [3290,3362)   fold GEMMs (inline fp32->bf16): Wcat_t rows 256..1151, wcombb_t
#define P1_BLOCKS 3362
__global__ __launch_bounds__(256) void prep(
    const float* __restrict__ x, const float* __restrict__ conv0_w,
    const float* __restrict__ conv0_b, const float* __restrict__ key_w,
    const float* __restrict__ key_b, const float* __restrict__ val_w,
    const float* __restrict__ val_b, const float* __restrict__ off_w,
    const float* __restrict__ off_b, const float* __restrict__ lin1_w,
    const float* __restrict__ lin2_w, const float* __restrict__ conv1_w,
    const float* __restrict__ conv1_b, const float* __restrict__ out_w,
    const float* __restrict__ out_b, const float* __restrict__ cam_emb,
    float* __restrict__ pos, u16* __restrict__ xtb_t, float* __restrict__ mu_x,
    u16* __restrict__ Wcat_t, float* __restrict__ bias_cat,
    u16* __restrict__ lin1b_t, u16* __restrict__ lin2b_t,
    u16* __restrict__ wcombb_t, float* __restrict__ bcomb,
    float* __restrict__ camoff, float* __restrict__ posy,
    float* __restrict__ posx) {
    __shared__ float sbuf[1088];
    __shared__ __align__(16) u16 As2[1024];   // fold A: [j][32 rows][8]
    __shared__ __align__(16) u16 Bs2[4096];   // fold B: [j][128 cols][8]
    int b = blockIdx.x, t = threadIdx.x;
    if (b < 800) {
        int hw = b, d = t;
        int h = hw / WW, w = hw % WW;
        int j = (d & 127) >> 1;
        float dim = powf(10000.0f, (float)j * (1.0f / 64.0f));
        float v;
        if (d < 128) v = (float)(h + 1) / (20.0f + 1e-6f) * (2.0f * (float)M_PI);
        else         v = (float)(w + 1) / (40.0f + 1e-6f) * (2.0f * (float)M_PI);
        float p = v / dim;
        pos[hw * DD + d] = (d & 1) ? cosf(p) : sinf(p);
    } else if (b < 1184) {
        int row = (b - 800) * 4 + (t >> 6);
        int lane = t & 63;
        const float* base = x + (size_t)row * HWSZ;
        float s = 0.f;
        for (int i = lane; i < HWSZ; i += 64) s += base[i];
#pragma unroll
        for (int m = 1; m <= 32; m <<= 1) s += __shfl_xor(s, m);
        if (lane == 0) mu_x[row] = s * (1.0f / (float)HWSZ);
    } else if (b < 1952) {
        int i = (b - 1184) * 256 + t;  // < 196608
        if (i < 65536) {
            int n = i >> 8, k = i & 255;
            Wcat_t[(((size_t)(k >> 3)) * 1152 + n) * 8 + (k & 7)] = f2b(conv0_w[i]);
            if (i < 256) bias_cat[i] = conv0_b[i];
        } else if (i < 131072) {
            int j = i - 65536;
            int n = j >> 8, k = j & 255;
            lin1b_t[(((size_t)(k >> 3)) * 256 + n) * 8 + (k & 7)] = f2b(lin1_w[j]);
        } else {
            int j = i - 131072;
            int n = j >> 8, k = j & 255;
            lin2b_t[(((size_t)(k >> 3)) * 256 + n) * 8 + (k & 7)] = f2b(lin2_w[j]);
        }
    } else if (b < 3152) {
        int idx = b - 1952;  // 0..1199
        int cam = idx / 200, rem = idx % 200;
        int hw0 = (rem % 25) * 32, c0 = (rem / 25) * 32;
        float (*tile)[33] = (float(*)[33])sbuf;
        int lhw = t & 31, lc4 = t >> 5;
#pragma unroll
        for (int i = 0; i < 4; ++i) {
            int lc = lc4 * 4 + i;
            tile[lc][lhw] = x[((size_t)(cam * DD + c0 + lc)) * HWSZ + hw0 + lhw];
        }
        __syncthreads();
        int lc2 = t & 31, lhw4 = t >> 5;
        int c = c0 + lc2;
#pragma unroll
        for (int i = 0; i < 4; ++i) {
            int lhw2 = lhw4 * 4 + i;
            int row = cam * HWSZ + hw0 + lhw2;
            xtb_t[(((size_t)(c >> 3)) * 4800 + row) * 8 + (c & 7)] =
                f2b(tile[lc2][lhw2]);
        }
    } else if (b < 3212) {
        int idx = b - 3152;  // 0..59
        int yside = (idx < 20);
        int coord = yside ? idx : idx - 20;
        if (t < 128) {
            int d = t, j = d >> 1;
            float dim = powf(10000.0f, (float)j * (1.0f / 64.0f));
            float v = yside
                ? (float)(coord + 1) / (20.0f + 1e-6f) * (2.0f * (float)M_PI)
                : (float)(coord + 1) / (40.0f + 1e-6f) * (2.0f * (float)M_PI);
            float p = v / dim;
            sbuf[d] = (d & 1) ? cosf(p) : sinf(p);
        }
        __syncthreads();
        int koff = yside ? 0 : 128;
        float* outp = yside ? (posy + coord * 384) : (posx + coord * 384);
        int l = t & 15, og = t >> 4;
#pragma unroll
        for (int chunk = 0; chunk < 24; ++chunk) {
            int n = chunk * 16 + og;
            const float* wr = off_w + (size_t)n * 256 + koff + l * 8;
            float4 w0 = *(const float4*)wr;
            float4 w1 = *(const float4*)(wr + 4);
            const float* pv = sbuf + l * 8;
            float s = pv[0] * w0.x + pv[1] * w0.y + pv[2] * w0.z + pv[3] * w0.w +
                      pv[4] * w1.x + pv[5] * w1.y + pv[6] * w1.z + pv[7] * w1.w;
            s = red16(s);
            if (l == 0) outp[n] = s;
        }
    } else if (b < 3218) {
        int cam = b - 3212;
        sbuf[t] = cam_emb[cam * DD + t];
        __syncthreads();
        int l = t & 15, og = t >> 4;
#pragma unroll
        for (int chunk = 0; chunk < 24; ++chunk) {
            int n = chunk * 16 + og;
            const float* wr = off_w + (size_t)n * 256 + l * 16;
            float s = 0.f;
#pragma unroll
            for (int i = 0; i < 4; ++i) {
                float4 w4 = *(const float4*)(wr + i * 4);
                const float* ce = sbuf + l * 16 + i * 4;
                s += ce[0] * w4.x + ce[1] * w4.y + ce[2] * w4.z + ce[3] * w4.w;
            }
            s = red16(s);
            if (l == 0) camoff[cam * 384 + n] = s;
        }
    } else if (b < 3274) {
        sbuf[t] = conv0_b[t];
        __syncthreads();
        int l = t & 15, og = t >> 4;
        int rr = (b - 3218) * 16 + og;  // 0..895
        const float* srcp;
        float bsrc;
        if (rr < 512) {
            int head = rr >> 6, cpair = (rr >> 1) & 31, kv = rr & 1;
            srcp = (kv ? val_w : key_w) + (size_t)(head * 32 + cpair) * 256;
            bsrc = (kv ? val_b : key_b)[head * 32 + cpair];
        } else {
            srcp = off_w + (size_t)(rr - 512) * 256;
            bsrc = off_b[rr - 512];
        }
        float s = 0.f;
#pragma unroll
        for (int i = 0; i < 4; ++i) {
            float4 w4 = *(const float4*)(srcp + l * 16 + i * 4);
            const float* cb = sbuf + l * 16 + i * 4;
            s += cb[0] * w4.x + cb[1] * w4.y + cb[2] * w4.z + cb[3] * w4.w;
        }
        s = red16(s);
        if (l == 0) bias_cat[256 + rr] = bsrc + s;
    } else if (b < 3290) {
        sbuf[t] = out_b[t];
        __syncthreads();
        int l = t & 15, og = t >> 4;
        int n = (b - 3274) * 16 + og;  // 0..255
        float s = 0.f;
#pragma unroll
        for (int i = 0; i < 4; ++i) {
            float4 w4 = *(const float4*)(conv1_w + (size_t)n * 256 + l * 16 + i * 4);
            const float* ob = sbuf + l * 16 + i * 4;
            s += ob[0] * w4.x + ob[1] * w4.y + ob[2] * w4.z + ob[3] * w4.w;
        }
        s = red16(s);
        if (l == 0) bcomb[n] = conv1_b[n] + s;
    } else {
        // fold GEMMs: 32x128 tiles, inline fp32->bf16 staging
        int fb = b - 3290;             // 0..71
        int isw = (fb >= 56);          // wcomb fold (16 blocks)
        int bb = isw ? fb - 56 : fb;
        int row0 = (bb >> 1) * 32, col0 = (bb & 1) * 128;
        int wv = t >> 6, lane = t & 63, quad = lane >> 4, l = lane & 15;
        f32x4 acc[2][2] = {};
        for (int k0 = 0; k0 < 256; k0 += 32) {
            __syncthreads();
            if (t < 128) {
                int m = t >> 2, j = t & 3;
                int rr = row0 + m;
                const float* ap;
                if (!isw) {
                    if (rr < 512) {
                        int head = rr >> 6, cpair = (rr >> 1) & 31, kv = rr & 1;
                        ap = (kv ? val_w : key_w) + (size_t)(head * 32 + cpair) * 256;
                    } else {
                        ap = off_w + (size_t)(rr - 512) * 256;
                    }
                } else {
                    ap = conv1_w + (size_t)rr * 256;
                }
                float4 f0 = *(const float4*)&ap[k0 + j * 8];
                float4 f1 = *(const float4*)&ap[k0 + j * 8 + 4];
                uint4 up;
                up.x = (u32)f2b(f0.x) | ((u32)f2b(f0.y) << 16);
                up.y = (u32)f2b(f0.z) | ((u32)f2b(f0.w) << 16);
                up.z = (u32)f2b(f1.x) | ((u32)f2b(f1.y) << 16);
                up.w = (u32)f2b(f1.z) | ((u32)f2b(f1.w) << 16);
                *(uint4*)&As2[(j * 32 + m) * 8] = up;
            }
            {
                // B[c][k] = W[k][c] (W = conv0_w or out_w), transpose to [j][c][8]
                int krel = t >> 3;                 // 0..31
                int k = k0 + krel;
                int j = t >> 6, kin = k & 7;
                int c0l = (t & 7) * 16;
                const float* wsrc = (isw ? out_w : conv0_w) + (size_t)k * 256 + col0 + c0l;
#pragma unroll
                for (int i = 0; i < 16; i += 4) {
                    float4 f = *(const float4*)&wsrc[i];
                    Bs2[(j * 128 + c0l + i) * 8 + kin]     = f2b(f.x);
                    Bs2[(j * 128 + c0l + i + 1) * 8 + kin] = f2b(f.y);
                    Bs2[(j * 128 + c0l + i + 2) * 8 + kin] = f2b(f.z);
                    Bs2[(j * 128 + c0l + i + 3) * 8 + kin] = f2b(f.w);
                }
            }
            __syncthreads();
            bf16x8 a0 = *(const bf16x8*)&As2[(quad * 32 + l) * 8];
            bf16x8 a1 = *(const bf16x8*)&As2[(quad * 32 + 16 + l) * 8];
            bf16x8 b0v = *(const bf16x8*)&Bs2[(quad * 128 + wv * 32 + l) * 8];
            bf16x8 b1v = *(const bf16x8*)&Bs2[(quad * 128 + wv * 32 + 16 + l) * 8];
            acc[0][0] = __builtin_amdgcn_mfma_f32_16x16x32_bf16(a0, b0v, acc[0][0], 0, 0, 0);
            acc[0][1] = __builtin_amdgcn_mfma_f32_16x16x32_bf16(a0, b1v, acc[0][1], 0, 0, 0);
            acc[1][0] = __builtin_amdgcn_mfma_f32_16x16x32_bf16(a1, b0v, acc[1][0], 0, 0, 0);
            acc[1][1] = __builtin_amdgcn_mfma_f32_16x16x32_bf16(a1, b1v, acc[1][1], 0, 0, 0);
        }
#pragma unroll
        for (int mt = 0; mt < 2; ++mt) {
#pragma unroll
            for (int nt = 0; nt < 2; ++nt) {
                int c = col0 + wv * 32 + nt * 16 + l;
#pragma unroll
                for (int r = 0; r < 4; ++r) {
                    int rr = row0 + mt * 16 + quad * 4 + r;
                    u16 ov = f2b(acc[mt][nt][r]);
                    if (!isw)
                        Wcat_t[(((size_t)(c >> 3)) * 1152 + 256 + rr) * 8 + (c & 7)] = ov;
                    else
                        wcombb_t[(((size_t)(c >> 3)) * 256 + rr) * 8 + (c & 7)] = ov;
                }
            }
        }
    }
}

// ---------------------------------------------------------------------------
// gemm_fused: blocks [0,675) BM=64 x BN=128 over Wcat_t (N=1152), k-major
// operands staged via global_load_lds. blocks [675,681): meang.
__global__ __launch_bounds__(256) void gemm_fused(
    const u16* __restrict__ Abt, const u16* __restrict__ Wcat_t,
    const float* __restrict__ bias_cat, const float* __restrict__ pos,
    const float* __restrict__ cam_emb, u16* __restrict__ spcb,
    u16* __restrict__ kvcat16, float* __restrict__ offs,
    const float* __restrict__ mu_x, const float* __restrict__ conv0_w,
    const float* __restrict__ conv0_b, const float* __restrict__ conv2_w,
    const float* __restrict__ conv2_b, float* __restrict__ g) {
    int b = blockIdx.x, t = threadIdx.x;
    if (b < 675) {
        __shared__ __align__(16) u16 As[2048];   // [j][64 rows][8]
        __shared__ __align__(16) u16 Bs[4096];   // [j][128 cols][8]
        int col0 = (b % 9) * 128, row0 = (b / 9) * 64;
        int wv = t >> 6, lane = t & 63;
        int quad = lane >> 4, l = lane & 15;
        f32x4 acc[4][2] = {};
        for (int kg = 0; kg < 32; kg += 4) {
            __syncthreads();
            gl_lds16(Abt + (((size_t)(kg + wv)) * 4800 + row0 + lane) * 8,
                     &As[wv * 64 * 8]);
            int jb = wv >> 1, hb = wv & 1;
            gl_lds16(Wcat_t + (((size_t)(kg + jb)) * 1152 + col0 + hb * 64 + lane) * 8,
                     &Bs[(jb * 128 + hb * 64) * 8]);
            gl_lds16(Wcat_t + (((size_t)(kg + 2 + jb)) * 1152 + col0 + hb * 64 + lane) * 8,
                     &Bs[((2 + jb) * 128 + hb * 64) * 8]);
            __syncthreads();
            bf16x8 b0 = *(const bf16x8*)&Bs[(quad * 128 + wv * 32 + l) * 8];
            bf16x8 b1 = *(const bf16x8*)&Bs[(quad * 128 + wv * 32 + 16 + l) * 8];
#pragma unroll
            for (int mt = 0; mt < 4; ++mt) {
                bf16x8 a = *(const bf16x8*)&As[(quad * 64 + mt * 16 + l) * 8];
                acc[mt][0] = __builtin_amdgcn_mfma_f32_16x16x32_bf16(a, b0, acc[mt][0], 0, 0, 0);
                acc[mt][1] = __builtin_amdgcn_mfma_f32_16x16x32_bf16(a, b1, acc[mt][1], 0, 0, 0);
            }
        }
#pragma unroll
        for (int mt = 0; mt < 4; ++mt) {
#pragma unroll
            for (int nt = 0; nt < 2; ++nt) {
                int col = col0 + wv * 32 + nt * 16 + l;
                float bb = bias_cat[col];
#pragma unroll
                for (int r = 0; r < 4; ++r) {
                    int row = row0 + mt * 16 + quad * 4 + r;
                    float v = acc[mt][nt][r] + bb;
                    if (col0 < 256) {
                        int cam = row / HWSZ, hw = row % HWSZ;
                        spcb[(size_t)row * 256 + col] =
                            f2b(v + pos[(size_t)hw * 256 + col] + cam_emb[cam * 256 + col]);
                    } else if (col0 < 768) {
                        kvcat16[(size_t)row * 512 + (col - 256)] = f2b(v);
                    } else {
                        offs[(size_t)row * 384 + (col - 768)] = v;
                    }
                }
            }
        }
    } else {
        int cam = b - 675;
        __shared__ float mu[DD];
        __shared__ float smu[DD];
        float pm;
        {
            int d = t;
            int j = (d & 127) >> 1;
            float inv = 1.0f / powf(10000.0f, (float)j * (1.0f / 64.0f));
            float s = 0.f;
            if (d < 128) {
                for (int h = 0; h < HH; ++h) {
                    float p = (float)(h + 1) / (20.0f + 1e-6f) * (2.0f * (float)M_PI) * inv;
                    s += (d & 1) ? cosf(p) : sinf(p);
                }
                pm = s * (1.0f / (float)HH);
            } else {
                for (int w = 0; w < WW; ++w) {
                    float p = (float)(w + 1) / (40.0f + 1e-6f) * (2.0f * (float)M_PI) * inv;
                    s += (d & 1) ? cosf(p) : sinf(p);
                }
                pm = s * (1.0f / (float)WW);
            }
        }
        mu[t] = mu_x[cam * DD + t];
        __syncthreads();
        float a = conv0_b[t] + pm + cam_emb[cam * DD + t];
        const float* wr = conv0_w + (size_t)t * DD;
        for (int k = 0; k < DD; ++k) a += mu[k] * wr[k];
        smu[t] = a;
        __syncthreads();
        float ga = conv2_b[t];
        const float* w2r = conv2_w + (size_t)t * DD;
        for (int d = 0; d < DD; ++d) ga += smu[d] * w2r[d];
        g[cam * DD + t] = ga;
    }
}

// ---------------------------------------------------------------------------
// Deformable attention: 2 q/block, 16 lanes/head, staged bilinear,
// bf16 kv gathers, 2-cam batched online softmax.
__global__ __launch_bounds__(256, 4) void attn_kernel(
    const u16* __restrict__ spcb, const u16* __restrict__ kvcat16,
    const float* __restrict__ offs, const float* __restrict__ posy,
    const float* __restrict__ posx, const float* __restrict__ camoff,
    const float* __restrict__ g, u16* __restrict__ attn_out) {
    int qq = blockIdx.x;
    int q0 = qq * 2;
    int tid = threadIdx.x;
    int cam = q0 / HWSZ;
    int hw0 = q0 % HWSZ;
    __shared__ float soff[2][384];
    __shared__ float wgt[2][192][4];
    __shared__ int   idxp[2][192][4];
    for (int i = tid; i < 768; i += 256) {
        int qi = i / 384, n = i - qi * 384;
        int hw = hw0 + qi;
        int h = hw / WW, w = hw - h * WW;
        soff[qi][n] = offs[(size_t)(q0 + qi) * 384 + n] + posy[h * 384 + n] +
                      posx[w * 384 + n] + camoff[cam * 384 + n];
    }
    __syncthreads();
    for (int e2 = tid; e2 < 384; e2 += 256) {
        int qi = e2 / 192, e = e2 - qi * 192;
        int head = e / 24, r = e - head * 24;
        int scam = r >> 2;
        int hw = hw0 + qi;
        int h = hw / WW, w = hw - h * WW;
        float X = (float)w + soff[qi][e * 2];
        float Y = (float)h + soff[qi][e * 2 + 1];
        float x0f = floorf(X), y0f = floorf(Y);
        float fx = X - x0f, fy = Y - y0f;
        int x0 = (int)x0f, y0 = (int)y0f, x1 = x0 + 1, y1 = y0 + 1;
        float vx0 = (x0 >= 0 && x0 < WW) ? 1.f : 0.f;
        float vx1 = (x1 >= 0 && x1 < WW) ? 1.f : 0.f;
        float vy0 = (y0 >= 0 && y0 < HH) ? 1.f : 0.f;
        float vy1 = (y1 >= 0 && y1 < HH) ? 1.f : 0.f;
        int cx0 = min(max(x0, 0), WW - 1), cx1 = min(max(x1, 0), WW - 1);
        int cy0 = min(max(y0, 0), HH - 1), cy1 = min(max(y1, 0), HH - 1);
        wgt[qi][e][0] = (1.f - fx) * (1.f - fy) * vx0 * vy0;
        wgt[qi][e][1] = fx * (1.f - fy) * vx1 * vy0;
        wgt[qi][e][2] = (1.f - fx) * fy * vx0 * vy1;
        wgt[qi][e][3] = fx * fy * vx1 * vy1;
        int pb = scam * HWSZ, hb = head * 64;
        idxp[qi][e][0] = ((pb + cy0 * WW + cx0) << 9) + hb;
        idxp[qi][e][1] = ((pb + cy0 * WW + cx1) << 9) + hb;
        idxp[qi][e][2] = ((pb + cy1 * WW + cx0) << 9) + hb;
        idxp[qi][e][3] = ((pb + cy1 * WW + cx1) << 9) + hb;
    }
    __syncthreads();
    int qi = tid >> 7, head = (tid >> 4) & 7, l = tid & 15;
    int q = q0 + qi;
    int c0 = l * 2;
    u32 qu = *(const u32*)&spcb[(size_t)q * 256 + head * 32 + c0];
    const float scale = 0.17677669529663687f;  // 1/sqrt(32)
    float q0s = lo2f(qu) * scale, q1s = hi2f(qu) * scale;
    float m = -1e30f, den = 0.f, o0 = 0.f, o1 = 0.f;
    int l4 = 4 * l;
    for (int scp = 0; scp < 3; ++scp) {
        int e0i = head * 24 + scp * 8;
        float av0[8], av1[8], lg[8];
#pragma unroll
        for (int p = 0; p < 8; ++p) {
            int e = e0i + p;
            float ak0 = 0.f, ak1 = 0.f, a0 = 0.f, a1 = 0.f;
#pragma unroll
            for (int j = 0; j < 4; ++j) {
                float wj = wgt[qi][e][j];
                int idx = idxp[qi][e][j] + l4;
                uint2 d = *(const uint2*)&kvcat16[idx];  // k0,v0,k1,v1
                ak0 += wj * lo2f(d.x);
                a0  += wj * hi2f(d.x);
                ak1 += wj * lo2f(d.y);
                a1  += wj * hi2f(d.y);
            }
            av0[p] = a0; av1[p] = a1;
            float pl = q0s * ak0 + q1s * ak1;
            lg[p] = red16(pl);
        }
        float2 gva = *(const float2*)&g[(scp * 2) * 256 + head * 32 + c0];
        float2 gvb = *(const float2*)&g[(scp * 2 + 1) * 256 + head * 32 + c0];
        float pga = red16(q0s * gva.x + q1s * gva.y);
        float pgb = red16(q0s * gvb.x + q1s * gvb.y);
        float mc = fmaxf(pga, pgb);
#pragma unroll
        for (int p = 0; p < 8; ++p) mc = fmaxf(mc, lg[p]);
        float mn = fmaxf(m, mc);
        float aa = __expf(m - mn);
        float ee[8];
        float dsum = 0.f, s0 = 0.f, s1 = 0.f;
#pragma unroll
        for (int p = 0; p < 8; ++p) {
            ee[p] = __expf(lg[p] - mn);
            dsum += ee[p];
            s0 += ee[p] * av0[p];
            s1 += ee[p] * av1[p];
        }
        float ea = __expf(pga - mn), eb = __expf(pgb - mn);
        dsum += ea + eb;
        s0 += ea * gva.x + eb * gvb.x;
        s1 += ea * gva.y + eb * gvb.y;
        den = den * aa + dsum;
        o0 = o0 * aa + s0;
        o1 = o1 * aa + s1;
        m = mn;
    }
    float inv = 1.f / den;
    u32 pack = (u32)f2b(o0 * inv) | ((u32)f2b(o1 * inv) << 16);
    *(u32*)&attn_out[(size_t)q * 256 + head * 32 + c0] = pack;
}

// ---------------------------------------------------------------------------
// Mega-epilogue (grid 300, 16 rows/block): comb+res+LN0 -> lin1+relu ->
// lin2+res+LN2 -> d_out (NCHW float4). Weights k-major via global_load_lds.
__global__ __launch_bounds__(256) void epilogue(
    const u16* __restrict__ Ab, const u16* __restrict__ Wc_t,
    const float* __restrict__ bcomb, const float* __restrict__ x_nchw,
    const float* __restrict__ n0g, const float* __restrict__ n0b,
    const u16* __restrict__ W1_t, const float* __restrict__ b1v,
    const u16* __restrict__ W2_t, const float* __restrict__ b2v,
    const float* __restrict__ n2g, const float* __restrict__ n2b,
    float* __restrict__ out_nchw) {
    __shared__ __align__(16) u16 As[552];
    __shared__ __align__(16) u16 Bs[8192];   // [j][256 cols][8]
    __shared__ __align__(16) u16 A2[4360];
    __shared__ float red[4][4][4][2];
    int t = threadIdx.x;
    int row0 = blockIdx.x * 16;
    int wv = t >> 6, lane = t & 63, quad = lane >> 4, l = lane & 15;
    int cam = row0 / HWSZ;
    int hw0q = row0 % HWSZ + quad * 4;

    // ---- GEMM1: comb ----
    f32x4 acc[4] = {};
    for (int kg = 0; kg < 32; kg += 4) {
        __syncthreads();
        if (t < 64) {
            int mm = t >> 2, j = t & 3;
            *(uint4*)&As[(j * 17 + mm) * 8] =
                *(const uint4*)&Ab[(size_t)(row0 + mm) * 256 + kg * 8 + j * 8];
        }
#pragma unroll
        for (int s = 0; s < 4; ++s)
            gl_lds16(Wc_t + (((size_t)(kg + wv)) * 256 + s * 64 + lane) * 8,
                     &Bs[(wv * 256 + s * 64) * 8]);
        __syncthreads();
        bf16x8 a = *(const bf16x8*)&As[(quad * 17 + l) * 8];
#pragma unroll
        for (int nt = 0; nt < 4; ++nt) {
            bf16x8 b = *(const bf16x8*)&Bs[(quad * 256 + wv * 64 + nt * 16 + l) * 8];
            acc[nt] = __builtin_amdgcn_mfma_f32_16x16x32_bf16(a, b, acc[nt], 0, 0, 0);
        }
    }
    float v[4][4];
    int cols[4];
#pragma unroll
    for (int nt = 0; nt < 4; ++nt) {
        int col = wv * 64 + nt * 16 + l;
        cols[nt] = col;
        float bb = bcomb[col];
        float4 rx = *(const float4*)&x_nchw[((size_t)(cam * 256 + col)) * HWSZ + hw0q];
        v[nt][0] = acc[nt][0] + bb + rx.x;
        v[nt][1] = acc[nt][1] + bb + rx.y;
        v[nt][2] = acc[nt][2] + bb + rx.z;
        v[nt][3] = acc[nt][3] + bb + rx.w;
    }
    // ---- LN0 ----
#pragma unroll
    for (int r = 0; r < 4; ++r) {
        float s = v[0][r] + v[1][r] + v[2][r] + v[3][r];
        float sq = v[0][r] * v[0][r] + v[1][r] * v[1][r] +
                   v[2][r] * v[2][r] + v[3][r] * v[3][r];
#pragma unroll
        for (int msk = 1; msk <= 8; msk <<= 1) {
            s += __shfl_xor(s, msk);
            sq += __shfl_xor(sq, msk);
        }
        if (l == 0) { red[wv][quad][r][0] = s; red[wv][quad][r][1] = sq; }
    }
    __syncthreads();
    float o0[4][4];
#pragma unroll
    for (int r = 0; r < 4; ++r) {
        float S = red[0][quad][r][0] + red[1][quad][r][0] +
                  red[2][quad][r][0] + red[3][quad][r][0];
        float Q = red[0][quad][r][1] + red[1][quad][r][1] +
                  red[2][quad][r][1] + red[3][quad][r][1];
        float mean = S * (1.0f / 256.0f);
        float var = Q * (1.0f / 256.0f) - mean * mean;
        float rstd = rsqrtf(var + 1e-5f);
        int row = quad * 4 + r;
#pragma unroll
        for (int nt = 0; nt < 4; ++nt) {
            int col = cols[nt];
            float ov = (v[nt][r] - mean) * rstd * n0g[col] + n0b[col];
            o0[nt][r] = ov;
            A2[((col >> 3) * 17 + row) * 8 + (col & 7)] = f2b(ov);
        }
    }
    // ---- GEMM2: lin1 ----
    f32x4 acc2[4] = {};
    for (int kg = 0; kg < 32; kg += 4) {
        __syncthreads();
#pragma unroll
        for (int s = 0; s < 4; ++s)
            gl_lds16(W1_t + (((size_t)(kg + wv)) * 256 + s * 64 + lane) * 8,
                     &Bs[(wv * 256 + s * 64) * 8]);
        __syncthreads();
        bf16x8 a = *(const bf16x8*)&A2[((kg + quad) * 17 + l) * 8];
#pragma unroll
        for (int nt = 0; nt < 4; ++nt) {
            bf16x8 b = *(const bf16x8*)&Bs[(quad * 256 + wv * 64 + nt * 16 + l) * 8];
            acc2[nt] = __builtin_amdgcn_mfma_f32_16x16x32_bf16(a, b, acc2[nt], 0, 0, 0);
        }
    }
    __syncthreads();
#pragma unroll
    for (int nt = 0; nt < 4; ++nt) {
        int col = cols[nt];
        float bb = b1v[col];
#pragma unroll
        for (int r = 0; r < 4; ++r) {
            int row = quad * 4 + r;
            A2[((col >> 3) * 17 + row) * 8 + (col & 7)] = f2b(fmaxf(acc2[nt][r] + bb, 0.f));
        }
    }
    // ---- GEMM3: lin2 ----
    f32x4 acc3[4] = {};
    for (int kg = 0; kg < 32; kg += 4) {
        __syncthreads();
#pragma unroll
        for (int s = 0; s < 4; ++s)
            gl_lds16(W2_t + (((size_t)(kg + wv)) * 256 + s * 64 + lane) * 8,
                     &Bs[(wv * 256 + s * 64) * 8]);
        __syncthreads();
        bf16x8 a = *(const bf16x8*)&A2[((kg + quad) * 17 + l) * 8];
#pragma unroll
        for (int nt = 0; nt < 4; ++nt) {
            bf16x8 b = *(const bf16x8*)&Bs[(quad * 256 + wv * 64 + nt * 16 + l) * 8];
            acc3[nt] = __builtin_amdgcn_mfma_f32_16x16x32_bf16(a, b, acc3[nt], 0, 0, 0);
        }
    }
    float v2[4][4];
#pragma unroll
    for (int nt = 0; nt < 4; ++nt) {
        float bb = b2v[cols[nt]];
#pragma unroll
        for (int r = 0; r < 4; ++r) v2[nt][r] = acc3[nt][r] + bb + o0[nt][r];
    }
    // ---- LN2 ----
    __syncthreads();
#pragma unroll
    for (int r = 0; r < 4; ++r) {
        float s = v2[0][r] + v2[1][r] + v2[2][r] + v2[3][r];
        float sq = v2[0][r] * v2[0][r] + v2[1][r] * v2[1][r] +
                   v2[2][r] * v2[2][r] + v2[3][r] * v2[3][r];
#pragma unroll
        for (int msk = 1; msk <= 8; msk <<= 1) {
            s += __shfl_xor(s, msk);
            sq += __shfl_xor(sq, msk);
        }
        if (l == 0) { red[wv][quad][r][0] = s; red[wv][quad][r][1] = sq; }
    }
    __syncthreads();
    float mean2[4], rstd2[4];
#pragma unroll
    for (int r = 0; r < 4; ++r) {
        float S = red[0][quad][r][0] + red[1][quad][r][0] +
                  red[2][quad][r][0] + red[3][quad][r][0];
        float Q = red[0][quad][r][1] + red[1][quad][r][1] +
                  red[2][quad][r][1] + red[3][quad][r][1];
        mean2[r] = S * (1.0f / 256.0f);
        float var = Q * (1.0f / 256.0f) - mean2[r] * mean2[r];
        rstd2[r] = rsqrtf(var + 1e-5f);
    }
#pragma unroll
    for (int nt = 0; nt < 4; ++nt) {
        int col = cols[nt];
        float gg = n2g[col], bb = n2b[col];
        float4 ov4;
        ov4.x = (v2[nt][0] - mean2[0]) * rstd2[0] * gg + bb;
        ov4.y = (v2[nt][1] - mean2[1]) * rstd2[1] * gg + bb;
        ov4.z = (v2[nt][2] - mean2[2]) * rstd2[2] * gg + bb;
        ov4.w = (v2[nt][3] - mean2[3]) * rstd2[3] * gg + bb;
        *(float4*)&out_nchw[((size_t)(cam * 256 + col)) * HWSZ + hw0q] = ov4;
    }
}

// ---------------------------------------------------------------------------
extern "C" void kernel_launch(void* const* d_in, const int* in_sizes, int n_in,
                              void* d_out, int out_size, void* d_ws, size_t ws_size,
                              hipStream_t stream) {
    const float* x       = (const float*)d_in[0];
    const float* conv0_w = (const float*)d_in[1];
    const float* conv0_b = (const float*)d_in[2];
    const float* conv2_w = (const float*)d_in[3];
    const float* conv2_b = (const float*)d_in[4];
    const float* cam_emb = (const float*)d_in[5];
    const float* off_w   = (const float*)d_in[6];
    const float* off_b   = (const float*)d_in[7];
    const float* val_w   = (const float*)d_in[8];
    const float* val_b   = (const float*)d_in[9];
    const float* key_w   = (const float*)d_in[10];
    const float* key_b   = (const float*)d_in[11];
    const float* out_w   = (const float*)d_in[12];
    const float* out_b   = (const float*)d_in[13];
    const float* conv1_w = (const float*)d_in[14];
    const float* conv1_b = (const float*)d_in[15];
    const float* norm0_g = (const float*)d_in[16];
    const float* norm0_b = (const float*)d_in[17];
    const float* lin1_w  = (const float*)d_in[18];
    const float* lin1_b  = (const float*)d_in[19];
    const float* lin2_w  = (const float*)d_in[20];
    const float* lin2_b  = (const float*)d_in[21];
    const float* norm2_g = (const float*)d_in[22];
    const float* norm2_b = (const float*)d_in[23];

    float* ws = (float*)d_ws;
    // sizes in FLOATS; u16 buffers use count/2 floats of space:
    // xtb_t 4800*256 u16 = 614400 f ; spcb 4800*256 u16 = 614400 f
    // kvcat 4800*512 u16 = 1228800 f ; Wcat_t 1152*256 u16 = 147456 f
    float* pos      = ws;                       // 204800
    float* mu_x     = pos + 204800;             // 1536
    float* g        = mu_x + 1536;              // 1536
    float* camoff   = g + 1536;                 // 2304
    float* posy     = camoff + 2304;            // 7680
    float* posx     = posy + 7680;              // 15360
    float* bias_cat = posx + 15360;             // 1152
    float* bcomb    = bias_cat + 1152;          // 256
    float* offs     = bcomb + 256;              // 1843200
    float* f_xtb    = offs + 1843200;           // 614400 (alias: attn_ob)
    float* f_spcb   = f_xtb + 614400;           // 614400
    float* f_kvcat  = f_spcb + 614400;          // 1228800
    float* f_Wcat   = f_kvcat + 1228800;        // 147456
    float* f_lin1b  = f_Wcat + 147456;          // 32768
    float* f_lin2b  = f_lin1b + 32768;          // 32768
    float* f_wcombb = f_lin2b + 32768;          // 32768

    u16* xtb_t    = (u16*)f_xtb;
    u16* spcb     = (u16*)f_spcb;
    u16* kvcat16  = (u16*)f_kvcat;
    u16* Wcat_t   = (u16*)f_Wcat;
    u16* lin1b_t  = (u16*)f_lin1b;
    u16* lin2b_t  = (u16*)f_lin2b;
    u16* wcombb_t = (u16*)f_wcombb;
    u16* attn_ob  = xtb_t;   // xtb dead after gemm_fused

    prep<<<P1_BLOCKS, 256, 0, stream>>>(
        x, conv0_w, conv0_b, key_w, key_b, val_w, val_b, off_w, off_b,
        lin1_w, lin2_w, conv1_w, conv1_b, out_w, out_b, cam_emb,
        pos, xtb_t, mu_x, Wcat_t, bias_cat, lin1b_t, lin2b_t, wcombb_t,
        bcomb, camoff, posy, posx);
    gemm_fused<<<681, 256, 0, stream>>>(xtb_t, Wcat_t, bias_cat, pos, cam_emb,
                                        spcb, kvcat16, offs, mu_x, conv0_w,
                                        conv0_b, conv2_w, conv2_b, g);
    attn_kernel<<<LQ / 2, 256, 0, stream>>>(spcb, kvcat16, offs, posy, posx,
                                            camoff, g, attn_ob);
    epilogue<<<300, 256, 0, stream>>>(attn_ob, wcombb_t, bcomb, x,
                                      norm0_g, norm0_b, lin1b_t, lin1_b,
                                      lin2b_t, lin2_b, norm2_g, norm2_b,
                                      (float*)d_out);
}